// Round 9
// baseline (1450.887 us; speedup 1.0000x reference)
//
#include <hip/hip_runtime.h>
#include <math.h>

// ---- problem constants ----
static constexpr int PDIM = 12800;      // 32ch*400
static constexpr int OSD  = 160;        // 10*16
static constexpr int NBLK_A = 200;      // it0 pass-A p-blocks (64 p each)

typedef _Float16 hv8  __attribute__((ext_vector_type(8)));
typedef float    f32x4 __attribute__((ext_vector_type(4)));

__device__ __forceinline__ void gload16(const void* g, void* l) {
    __builtin_amdgcn_global_load_lds(
        (const __attribute__((address_space(1))) void*)g,
        (__attribute__((address_space(3))) void*)l, 16, 0, 0);
}

// ---------------- K0: prim_w[co][ci][81] -> Wk1/Wk2[k][co][ci] fp16 planes ----------------
__global__ void k_prep_w(const float* __restrict__ w,
                         _Float16* __restrict__ Wk1, _Float16* __restrict__ Wk2) {
    __shared__ float s[20736];          // one co-slice: [ci=256][k=81]
    int co = blockIdx.x, t = threadIdx.x;
    const float4* src = (const float4*)(w + (size_t)co*20736);
    float4* d4 = (float4*)s;
    for (int i = t; i < 5184; i += 256) d4[i] = src[i];
    __syncthreads();
    for (int k = 0; k < 81; ++k) {
        float val = s[t*81 + k];
        _Float16 h1 = (_Float16)val;
        _Float16 h2 = (_Float16)(val - (float)h1);
        size_t o = (size_t)k*65536 + co*256 + t;
        Wk1[o] = h1;
        Wk2[o] = h2;
    }
}

// ---------------- K1: conv1 + bias + relu -> ht planes [b][pos][co] fp16 x2 ----------------
__global__ void k_conv1(const float* __restrict__ x, const float* __restrict__ w,
                        const float* __restrict__ bias,
                        _Float16* __restrict__ ht1, _Float16* __restrict__ ht2) {
    __shared__ float sx[1296];
    __shared__ float sw[1296];
    int b = blockIdx.x, cog = blockIdx.y;
    int tid = threadIdx.x;
    for (int i = tid; i < 1296; i += 256) {
        sx[i] = x[b*1296 + i];
        sw[i] = w[cog*1296 + i];
    }
    __syncthreads();
    for (int pos = tid; pos < 784; pos += 256) {
        int y = pos / 28, xx = pos - y*28;
        float acc[16];
        #pragma unroll
        for (int c = 0; c < 16; ++c) acc[c] = 0.f;
        for (int ky = 0; ky < 9; ++ky) {
            #pragma unroll
            for (int kx = 0; kx < 9; ++kx) {
                float xv = sx[(y+ky)*36 + xx + kx];
                #pragma unroll
                for (int c = 0; c < 16; ++c)
                    acc[c] += xv * sw[c*81 + ky*9 + kx];
            }
        }
        #pragma unroll
        for (int c = 0; c < 16; ++c) {
            float r = acc[c] + bias[cog*16 + c];
            r = r > 0.f ? r : 0.f;
            _Float16 h1 = (_Float16)r;
            float q1 = r - (float)h1;
            _Float16 h2 = (_Float16)q1;
            size_t o = ((size_t)b*784 + pos)*256 + cog*16 + c;
            ht1[o] = h1; ht2[o] = h2;
        }
    }
}

// ---------------- K2: primary conv as 81 shifted GEMMs, fp16 2-plane split MFMA ----------------
// ROUND-5 CONFIG (best measured): BM=128 BN=128 BK=32, 512 thr (8 waves 2x4, wave 64x32),
// dbuf 64KB -> 2 blocks/CU, __syncthreads 2-phase, ksplit=8 atomics.
__global__ __launch_bounds__(512, 4) void k_prim_mfma(
        const _Float16* __restrict__ ht1, const _Float16* __restrict__ ht2,
        const _Float16* __restrict__ Wk1, const _Float16* __restrict__ Wk2,
        float* __restrict__ Clin) {
    // per-buffer (halfs): A1 @0 (4096), A2 @4096, B1 @8192, B2 @12288; BUF=16384
    __shared__ _Float16 lds[32768];
    const int t   = threadIdx.x;
    const int n0  = blockIdx.x * 128;
    const int co0 = blockIdx.y * 128;
    const int z   = blockIdx.z;
    const int klo = (z*81) >> 3, khi = ((z+1)*81) >> 3;
    const int NSTEP = (khi - klo) * 8;

    // staging precompute (source-pre-swizzled ci-group, LDS dest lane-linear)
    const int srow = t >> 2, slot = t & 3;
    const int g = slot ^ ((srow >> 1) & 3);
    const size_t aSrcOff = (size_t)(co0 + srow)*256 + g*8;
    const int n1 = n0 + srow;
    const int b1 = n1/400, rr1 = n1 - b1*400, y1 = rr1/20, x1 = rr1 - y1*20;
    const size_t bOff1 = ((size_t)b1*784 + y1*28 + x1)*256 + g*8;

    // compute-side: 8 waves 2x4, wave tile 64x32
    const int l = t & 63, w8 = t >> 6;
    const int wm = w8 >> 2, wn = w8 & 3;
    const int lm = l & 15, lk = l >> 4;
    int aoff[4], boff[2];
    #pragma unroll
    for (int i = 0; i < 4; ++i) {
        int ra = wm*64 + i*16 + lm;
        aoff[i] = ra*32 + ((lk ^ ((ra>>1)&3))*8);
    }
    #pragma unroll
    for (int j = 0; j < 2; ++j) {
        int rb = wn*32 + j*16 + lm;
        boff[j] = 8192 + rb*32 + ((lk ^ ((rb>>1)&3))*8);
    }

    f32x4 acc[4][2];
    #pragma unroll
    for (int i = 0; i < 4; ++i)
        #pragma unroll
        for (int j = 0; j < 2; ++j) { acc[i][j][0]=0.f; acc[i][j][1]=0.f; acc[i][j][2]=0.f; acc[i][j][3]=0.f; }

#define ASTAGE(S, LB) { int k_ = klo + ((S) >> 3), c_ = (S) & 7; \
        size_t ao = (size_t)k_*65536 + c_*32 + aSrcOff; \
        gload16(Wk1 + ao, (LB) + t*8); \
        gload16(Wk2 + ao, (LB) + 4096 + t*8); }

#define BGLOAD(S, LB) { int k_ = klo + ((S) >> 3), c_ = (S) & 7; \
        int spk_ = (k_/9)*28 + (k_ - (k_/9)*9); \
        size_t so = (size_t)spk_*256 + c_*32; \
        gload16(ht1 + bOff1 + so, (LB) + 8192  + t*8); \
        gload16(ht2 + bOff1 + so, (LB) + 12288 + t*8); }

#define COMPUTE(L) { hv8 a1[4], a2[4]; \
        _Pragma("unroll") for (int mi = 0; mi < 4; ++mi) { \
            a1[mi] = *(const hv8*)((L) + aoff[mi]); \
            a2[mi] = *(const hv8*)((L) + 4096 + aoff[mi]); } \
        _Pragma("unroll") for (int nj = 0; nj < 2; ++nj) { \
            hv8 q1 = *(const hv8*)((L) + boff[nj]); \
            hv8 q2 = *(const hv8*)((L) + 4096 + boff[nj]); \
            _Pragma("unroll") for (int mi = 0; mi < 4; ++mi) { \
                f32x4 c = acc[mi][nj]; \
                c = __builtin_amdgcn_mfma_f32_16x16x32_f16(a1[mi], q1, c, 0, 0, 0); \
                c = __builtin_amdgcn_mfma_f32_16x16x32_f16(a1[mi], q2, c, 0, 0, 0); \
                c = __builtin_amdgcn_mfma_f32_16x16x32_f16(a2[mi], q1, c, 0, 0, 0); \
                acc[mi][nj] = c; } } }

    // prologue: stage step 0 into buf0
    ASTAGE(0, lds); BGLOAD(0, lds);
    __syncthreads();

    for (int s = 0; s < NSTEP; ++s) {
        const int d = s & 1;
        _Float16* Lnext = lds + (d ? 0 : 16384);
        const _Float16* L = lds + (d ? 16384 : 0);
        if ((s + 1) < NSTEP) { ASTAGE(s+1, Lnext); BGLOAD(s+1, Lnext); }
        COMPUTE(L);
        __syncthreads();
    }

    // epilogue: atomic accumulate into Clin[co][n]
    #pragma unroll
    for (int mi = 0; mi < 4; ++mi) {
        #pragma unroll
        for (int nj = 0; nj < 2; ++nj) {
            int nn = n0 + wn*32 + nj*16 + lm;
            #pragma unroll
            for (int r = 0; r < 4; ++r) {
                int co = co0 + wm*64 + mi*16 + lk*4 + r;
                atomicAdd(&Clin[(size_t)co*12800 + nn], acc[mi][nj][r]);
            }
        }
    }
#undef ASTAGE
#undef BGLOAD
#undef COMPUTE
}

// ---------------- K2b: squared-norm partials per (b,u) from Clin+bias (no up write) ----------------
__global__ void k_ssq(const float* __restrict__ Clin, const float* __restrict__ bias,
                      float* __restrict__ ssq) {
    __shared__ float r0[256], r1[256];
    int tid = threadIdx.x;
    int e = blockIdx.x*256 + tid;
    int co = e / 12800, n = e - co*12800;
    int unit = co >> 5;
    int bn = n / 400;
    float val = Clin[e] + bias[co];
    int n0b = (blockIdx.x % 50) * 256;
    int bn0 = n0b / 400;
    int nb  = (bn0+1)*400 - n0b;
    float v2 = val * val;
    bool hi = (tid >= nb);
    r0[tid] = hi ? 0.f : v2;
    r1[tid] = hi ? v2 : 0.f;
    __syncthreads();
    for (int st = 128; st > 0; st >>= 1) {
        if (tid < st) { r0[tid] += r0[tid+st]; r1[tid] += r1[tid+st]; }
        __syncthreads();
    }
    if (tid == 0) {
        atomicAdd(&ssq[bn0*8 + unit], r0[0]);
        if (nb < 256) atomicAdd(&ssq[(bn0+1)*8 + unit], r1[0]);
    }
    (void)bn;
}

// ---------------- K3: xq[p][b*8+u] = (Clin[co][n]+bias)*scl(b,u) ----------------
__global__ void k_xq2(const float* __restrict__ Clin, const float* __restrict__ bias,
                      const float* __restrict__ ssq, float* __restrict__ xq) {
    __shared__ float sT[32][257];
    __shared__ float sS[256];
    int p0 = blockIdx.x*32, tid = threadIdx.x;
    {
        float q = ssq[tid];
        sS[tid] = sqrtf(q) / (1.f + q);
    }
    __syncthreads();
    for (int r = 0; r < 32; ++r) {
        int e = r*256 + tid;
        int bu = e >> 5, pi = e & 31;
        int p = p0 + pi;
        int ch = p / 400, rr = p - ch*400;
        int unit = bu & 7, bn = bu >> 3;
        int co = unit*32 + ch;
        sT[pi][bu] = (Clin[(size_t)co*12800 + bn*400 + rr] + bias[co]) * sS[bu];
    }
    __syncthreads();
    for (int r = 0; r < 32; ++r)
        xq[(size_t)(p0+r)*256 + tid] = sT[r][tid];
}

// ---------------- K5: it0 pass A — uniform c=1/12800, partial s_j ----------------
// grid (NBLK_A, 2): x = 64-p block, y = 80-os half. 256 thr = 8 g (10 os each) x 32 bq.
__global__ __launch_bounds__(256) void k_route_sj(const float* __restrict__ Wd,
        const float* __restrict__ xq, float* __restrict__ sjp) {
    int tid = threadIdx.x;
    int bq = tid & 31, g = tid >> 5;
    int os0 = blockIdx.y*80 + g*10;
    float acc[10];
    #pragma unroll
    for (int i = 0; i < 10; ++i) acc[i] = 0.f;
    int p0 = blockIdx.x * 64;
    for (int p = p0; p < p0+64; ++p) {
        const float4* xr = (const float4*)(xq + (size_t)p*256 + bq*8);
        float4 xa = xr[0], xb = xr[1];
        const float4* wr = (const float4*)(Wd + (size_t)p*1280 + os0*8);
        #pragma unroll
        for (int i = 0; i < 10; ++i) {
            float4 w0 = wr[i*2], w1 = wr[i*2+1];
            float uh = w0.x*xa.x + w0.y*xa.y + w0.z*xa.z + w0.w*xa.w
                     + w1.x*xb.x + w1.y*xb.y + w1.z*xb.z + w1.w*xb.w;
            acc[i] += uh;
        }
    }
    const float uc = 1.f / 12800.f;
    float* outp = sjp + (size_t)blockIdx.x*5120 + bq*OSD + os0;
    #pragma unroll
    for (int i = 0; i < 10; ++i) outp[i] = acc[i] * uc;
}

// ---------------- K6: reduce np partials -> s_j (/cden if useDen) -> squash over O -> v ----------------
__global__ void k_reduce_squash(const float* __restrict__ sjp, float* __restrict__ v,
                                const float* __restrict__ cden, int useDen, int np,
                                float* __restrict__ dout, int writeOut) {
    __shared__ float ss[640];
    __shared__ float sc[64];
    int tid = threadIdx.x;
    int e = blockIdx.x*640 + tid;
    float s = 0.f;
    for (int k = 0; k < np; ++k) s += sjp[(size_t)k*5120 + e];
    if (useDen) {
        int o = (tid % 160) >> 4;
        s *= 1.f / cden[o];
    }
    ss[tid] = s;
    __syncthreads();
    if (tid < 64) {
        int bl = tid >> 4, sl = tid & 15;
        float msq = 0.f;
        #pragma unroll
        for (int o = 0; o < 10; ++o) { float t_ = ss[bl*160 + o*16 + sl]; msq += t_*t_; }
        sc[tid] = sqrtf(msq) / (1.f + msq);
    }
    __syncthreads();
    int bl = tid / 160, r = tid - bl*160, sl = r & 15;
    float val = ss[tid] * sc[bl*16 + sl];
    v[e] = val;
    if (writeOut) dout[e] = val;
}

// ---------------- K7: fused agree/bij-update + next-iteration unnormalized s_j ----------------
// thread = (b = tid/10, o = tid%10). Per p (32 per block): u_hat[b,p,o,0..15] computed ONCE
// into registers; used for agree (LDS reduce over b -> leader updates bij, exp -> LDS)
// AND for acc2[s] += e * uh[s] (the next s_j, normalized later by cden in reduce_squash).
__global__ __launch_bounds__(320) void k_fused2(const float* __restrict__ Wd,
        const float* __restrict__ xq, const float* __restrict__ v,
        float* __restrict__ bij, float* __restrict__ cden, float* __restrict__ sjp) {
    __shared__ float sxq[32*260];
    __shared__ float ag[320];
    __shared__ float se[16];
    int tid = threadIdx.x;
    int p0 = blockIdx.x*32;
    int o = tid % 10, b = tid / 10;
    for (int e = tid; e < 8192; e += 320) {
        int pl = e >> 8, bu = e & 255;
        sxq[pl*260 + bu] = xq[(size_t)(p0+pl)*256 + bu];
    }
    const float4* vp = (const float4*)&v[b*160 + o*16];
    float4 vr0 = vp[0], vr1 = vp[1], vr2 = vp[2], vr3 = vp[3];
    __syncthreads();

    float acc2[16];
    #pragma unroll
    for (int s = 0; s < 16; ++s) acc2[s] = 0.f;
    float cden_acc = 0.f;

    for (int pl = 0; pl < 32; ++pl) {
        int p = p0 + pl;
        const float4* wr = (const float4*)(Wd + (size_t)p*1280 + o*128);
        float4 x0 = *(const float4*)&sxq[pl*260 + b*8];
        float4 x1 = *(const float4*)&sxq[pl*260 + b*8 + 4];
        float uh[16];
        #pragma unroll
        for (int s = 0; s < 16; ++s) {
            float4 w0 = wr[s*2], w1 = wr[s*2+1];
            uh[s] = w0.x*x0.x + w0.y*x0.y + w0.z*x0.z + w0.w*x0.w
                  + w1.x*x1.x + w1.y*x1.y + w1.z*x1.z + w1.w*x1.w;
        }
        float agp = uh[0]*vr0.x + uh[1]*vr0.y + uh[2]*vr0.z + uh[3]*vr0.w
                  + uh[4]*vr1.x + uh[5]*vr1.y + uh[6]*vr1.z + uh[7]*vr1.w
                  + uh[8]*vr2.x + uh[9]*vr2.y + uh[10]*vr2.z + uh[11]*vr2.w
                  + uh[12]*vr3.x + uh[13]*vr3.y + uh[14]*vr3.z + uh[15]*vr3.w;
        ag[tid] = agp;
        __syncthreads();
        if (tid < 10) {
            float s_ = 0.f;
            #pragma unroll
            for (int bb = 0; bb < 32; ++bb) s_ += ag[tid + bb*10];
            float bn_ = bij[p*10 + tid] + s_ * (1.f/32.f);
            bij[p*10 + tid] = bn_;
            float e_ = __expf(bn_);
            se[tid] = e_;
            cden_acc += e_;
        }
        __syncthreads();
        float ee = se[o];
        #pragma unroll
        for (int s = 0; s < 16; ++s) acc2[s] += ee * uh[s];
    }

    if (tid < 10) atomicAdd(&cden[tid], cden_acc);
    float* outp = sjp + (size_t)blockIdx.x*5120 + b*160 + o*16;
    #pragma unroll
    for (int s = 0; s < 16; ++s) outp[s] = acc2[s];
}

extern "C" void kernel_launch(void* const* d_in, const int* in_sizes, int n_in,
                              void* d_out, int out_size, void* d_ws, size_t ws_size,
                              hipStream_t stream) {
    const float* x   = (const float*)d_in[0];
    const float* c1w = (const float*)d_in[1];
    const float* c1b = (const float*)d_in[2];
    const float* pw  = (const float*)d_in[3];
    const float* pb  = (const float*)d_in[4];
    const float* Wd  = (const float*)d_in[5];
    float* out = (float*)d_out;

    // workspace map (bytes)
    char* wsb = (char*)d_ws;
    _Float16* ht1 = (_Float16*)(wsb);                 // 12,845,056
    _Float16* ht2 = (_Float16*)(wsb + 12845056);      // 12,845,056
    _Float16* Wk1 = (_Float16*)(wsb + 25690112);      // 10,616,832
    _Float16* Wk2 = (_Float16*)(wsb + 36306944);      // 10,616,832
    float* Clin = (float*)(wsb + 46923776);           // 13,107,200
    char* tailb = wsb + 60030976;
    float* bij   = (float*)tailb;                     // 128000 f
    float* ssq   = bij + 128000;                      // 256 f
    float* cdenA = ssq + 256;                         // 16 f
    float* cdenB = cdenA + 16;                        // 16 f
    float* vv    = cdenB + 16;                        // 5120 f
    // aliases over dead regions:
    float* xq  = (float*)(wsb);              // over ht planes (dead after GEMM); 13.1MB
    float* sjp = (float*)(wsb + 46923776);   // over Clin (dead after xq2); 400*5120 f = 8.2MB

    hipMemsetAsync(Clin, 0, 13107200, stream);
    hipMemsetAsync(bij, 0, (128000 + 256 + 32)*sizeof(float), stream);  // bij+ssq+cdenA+cdenB

    k_prep_w<<<256, 256, 0, stream>>>(pw, Wk1, Wk2);
    k_conv1<<<dim3(32,16), 256, 0, stream>>>(x, c1w, c1b, ht1, ht2);
    k_prim_mfma<<<dim3(100,2,8), 512, 0, stream>>>(ht1, ht2, Wk1, Wk2, Clin);
    k_ssq<<<12800, 256, 0, stream>>>(Clin, pb, ssq);
    k_xq2<<<400, 256, 0, stream>>>(Clin, pb, ssq, xq);

    // it0: uniform coupling (bij = 0)
    k_route_sj<<<dim3(NBLK_A,2), 256, 0, stream>>>(Wd, xq, sjp);
    k_reduce_squash<<<8, 640, 0, stream>>>(sjp, vv, cdenA, 0, NBLK_A, out, 0);
    // it1: fused agree+bij-update+s~_j (u_hat computed once)
    k_fused2<<<400, 320, 0, stream>>>(Wd, xq, vv, bij, cdenA, sjp);
    k_reduce_squash<<<8, 640, 0, stream>>>(sjp, vv, cdenA, 1, 400, out, 0);
    // it2
    k_fused2<<<400, 320, 0, stream>>>(Wd, xq, vv, bij, cdenB, sjp);
    k_reduce_squash<<<8, 640, 0, stream>>>(sjp, vv, cdenB, 1, 400, out, 1);
}

// Round 10
// 986.099 us; speedup vs baseline: 1.4713x; 1.4713x over previous
//
#include <hip/hip_runtime.h>
#include <math.h>

// ---- problem constants ----
static constexpr int PDIM = 12800;      // 32ch*400
static constexpr int OSD  = 160;        // 10*16
static constexpr int NBLK_A = 200;      // pass-A p-blocks (64 p each)

typedef _Float16 hv8  __attribute__((ext_vector_type(8)));
typedef float    f32x4 __attribute__((ext_vector_type(4)));

__device__ __forceinline__ void gload16(const void* g, void* l) {
    __builtin_amdgcn_global_load_lds(
        (const __attribute__((address_space(1))) void*)g,
        (__attribute__((address_space(3))) void*)l, 16, 0, 0);
}

// ---------------- K0: prim_w[co][ci][81] -> Wk1/Wk2[k][co][ci] fp16 planes ----------------
__global__ void k_prep_w(const float* __restrict__ w,
                         _Float16* __restrict__ Wk1, _Float16* __restrict__ Wk2) {
    __shared__ float s[20736];          // one co-slice: [ci=256][k=81]
    int co = blockIdx.x, t = threadIdx.x;
    const float4* src = (const float4*)(w + (size_t)co*20736);
    float4* d4 = (float4*)s;
    for (int i = t; i < 5184; i += 256) d4[i] = src[i];
    __syncthreads();
    for (int k = 0; k < 81; ++k) {
        float val = s[t*81 + k];
        _Float16 h1 = (_Float16)val;
        _Float16 h2 = (_Float16)(val - (float)h1);
        size_t o = (size_t)k*65536 + co*256 + t;
        Wk1[o] = h1;
        Wk2[o] = h2;
    }
}

// ---------------- K1: conv1 + bias + relu -> ht planes [b][pos][co] fp16 x2 ----------------
__global__ void k_conv1(const float* __restrict__ x, const float* __restrict__ w,
                        const float* __restrict__ bias,
                        _Float16* __restrict__ ht1, _Float16* __restrict__ ht2) {
    __shared__ float sx[1296];
    __shared__ float sw[1296];
    int b = blockIdx.x, cog = blockIdx.y;
    int tid = threadIdx.x;
    for (int i = tid; i < 1296; i += 256) {
        sx[i] = x[b*1296 + i];
        sw[i] = w[cog*1296 + i];
    }
    __syncthreads();
    for (int pos = tid; pos < 784; pos += 256) {
        int y = pos / 28, xx = pos - y*28;
        float acc[16];
        #pragma unroll
        for (int c = 0; c < 16; ++c) acc[c] = 0.f;
        for (int ky = 0; ky < 9; ++ky) {
            #pragma unroll
            for (int kx = 0; kx < 9; ++kx) {
                float xv = sx[(y+ky)*36 + xx + kx];
                #pragma unroll
                for (int c = 0; c < 16; ++c)
                    acc[c] += xv * sw[c*81 + ky*9 + kx];
            }
        }
        #pragma unroll
        for (int c = 0; c < 16; ++c) {
            float r = acc[c] + bias[cog*16 + c];
            r = r > 0.f ? r : 0.f;
            _Float16 h1 = (_Float16)r;
            float q1 = r - (float)h1;
            _Float16 h2 = (_Float16)q1;
            size_t o = ((size_t)b*784 + pos)*256 + cog*16 + c;
            ht1[o] = h1; ht2[o] = h2;
        }
    }
}

// ---------------- K2: primary conv as 81 shifted GEMMs, fp16 2-plane split MFMA ----------------
// ROUND-5 CONFIG (best measured ~427us): BM=128 BN=128 BK=32, 512 thr (8 waves 2x4, wave
// 64x32), dbuf 64KB -> 2 blocks/CU, __syncthreads 2-phase, ksplit=8 atomics.
__global__ __launch_bounds__(512, 4) void k_prim_mfma(
        const _Float16* __restrict__ ht1, const _Float16* __restrict__ ht2,
        const _Float16* __restrict__ Wk1, const _Float16* __restrict__ Wk2,
        float* __restrict__ Clin) {
    // per-buffer (halfs): A1 @0 (4096), A2 @4096, B1 @8192, B2 @12288; BUF=16384
    __shared__ _Float16 lds[32768];
    const int t   = threadIdx.x;
    const int n0  = blockIdx.x * 128;
    const int co0 = blockIdx.y * 128;
    const int z   = blockIdx.z;
    const int klo = (z*81) >> 3, khi = ((z+1)*81) >> 3;
    const int NSTEP = (khi - klo) * 8;

    // staging precompute (source-pre-swizzled ci-group, LDS dest lane-linear)
    const int srow = t >> 2, slot = t & 3;
    const int g = slot ^ ((srow >> 1) & 3);
    const size_t aSrcOff = (size_t)(co0 + srow)*256 + g*8;
    const int n1 = n0 + srow;
    const int b1 = n1/400, rr1 = n1 - b1*400, y1 = rr1/20, x1 = rr1 - y1*20;
    const size_t bOff1 = ((size_t)b1*784 + y1*28 + x1)*256 + g*8;

    // compute-side: 8 waves 2x4, wave tile 64x32
    const int l = t & 63, w8 = t >> 6;
    const int wm = w8 >> 2, wn = w8 & 3;
    const int lm = l & 15, lk = l >> 4;
    int aoff[4], boff[2];
    #pragma unroll
    for (int i = 0; i < 4; ++i) {
        int ra = wm*64 + i*16 + lm;
        aoff[i] = ra*32 + ((lk ^ ((ra>>1)&3))*8);
    }
    #pragma unroll
    for (int j = 0; j < 2; ++j) {
        int rb = wn*32 + j*16 + lm;
        boff[j] = 8192 + rb*32 + ((lk ^ ((rb>>1)&3))*8);
    }

    f32x4 acc[4][2];
    #pragma unroll
    for (int i = 0; i < 4; ++i)
        #pragma unroll
        for (int j = 0; j < 2; ++j) { acc[i][j][0]=0.f; acc[i][j][1]=0.f; acc[i][j][2]=0.f; acc[i][j][3]=0.f; }

#define ASTAGE(S, LB) { int k_ = klo + ((S) >> 3), c_ = (S) & 7; \
        size_t ao = (size_t)k_*65536 + c_*32 + aSrcOff; \
        gload16(Wk1 + ao, (LB) + t*8); \
        gload16(Wk2 + ao, (LB) + 4096 + t*8); }

#define BGLOAD(S, LB) { int k_ = klo + ((S) >> 3), c_ = (S) & 7; \
        int spk_ = (k_/9)*28 + (k_ - (k_/9)*9); \
        size_t so = (size_t)spk_*256 + c_*32; \
        gload16(ht1 + bOff1 + so, (LB) + 8192  + t*8); \
        gload16(ht2 + bOff1 + so, (LB) + 12288 + t*8); }

#define COMPUTE(L) { hv8 a1[4], a2[4]; \
        _Pragma("unroll") for (int mi = 0; mi < 4; ++mi) { \
            a1[mi] = *(const hv8*)((L) + aoff[mi]); \
            a2[mi] = *(const hv8*)((L) + 4096 + aoff[mi]); } \
        _Pragma("unroll") for (int nj = 0; nj < 2; ++nj) { \
            hv8 q1 = *(const hv8*)((L) + boff[nj]); \
            hv8 q2 = *(const hv8*)((L) + 4096 + boff[nj]); \
            _Pragma("unroll") for (int mi = 0; mi < 4; ++mi) { \
                f32x4 c = acc[mi][nj]; \
                c = __builtin_amdgcn_mfma_f32_16x16x32_f16(a1[mi], q1, c, 0, 0, 0); \
                c = __builtin_amdgcn_mfma_f32_16x16x32_f16(a1[mi], q2, c, 0, 0, 0); \
                c = __builtin_amdgcn_mfma_f32_16x16x32_f16(a2[mi], q1, c, 0, 0, 0); \
                acc[mi][nj] = c; } } }

    // prologue: stage step 0 into buf0
    ASTAGE(0, lds); BGLOAD(0, lds);
    __syncthreads();

    for (int s = 0; s < NSTEP; ++s) {
        const int d = s & 1;
        _Float16* Lnext = lds + (d ? 0 : 16384);
        const _Float16* L = lds + (d ? 16384 : 0);
        if ((s + 1) < NSTEP) { ASTAGE(s+1, Lnext); BGLOAD(s+1, Lnext); }
        COMPUTE(L);
        __syncthreads();
    }

    // epilogue: atomic accumulate into Clin[co][n]
    #pragma unroll
    for (int mi = 0; mi < 4; ++mi) {
        #pragma unroll
        for (int nj = 0; nj < 2; ++nj) {
            int nn = n0 + wn*32 + nj*16 + lm;
            #pragma unroll
            for (int r = 0; r < 4; ++r) {
                int co = co0 + wm*64 + mi*16 + lk*4 + r;
                atomicAdd(&Clin[(size_t)co*12800 + nn], acc[mi][nj][r]);
            }
        }
    }
#undef ASTAGE
#undef BGLOAD
#undef COMPUTE
}

// ---------------- K2b: squared-norm partials per (b,u) from Clin+bias ----------------
__global__ void k_ssq(const float* __restrict__ Clin, const float* __restrict__ bias,
                      float* __restrict__ ssq) {
    __shared__ float r0[256], r1[256];
    int tid = threadIdx.x;
    int e = blockIdx.x*256 + tid;
    int co = e / 12800;
    int unit = co >> 5;
    float val = Clin[e] + bias[co];
    int n0b = (blockIdx.x % 50) * 256;
    int bn0 = n0b / 400;
    int nb  = (bn0+1)*400 - n0b;
    float v2 = val * val;
    bool hi = (tid >= nb);
    r0[tid] = hi ? 0.f : v2;
    r1[tid] = hi ? v2 : 0.f;
    __syncthreads();
    for (int st = 128; st > 0; st >>= 1) {
        if (tid < st) { r0[tid] += r0[tid+st]; r1[tid] += r1[tid+st]; }
        __syncthreads();
    }
    if (tid == 0) {
        atomicAdd(&ssq[bn0*8 + unit], r0[0]);
        if (nb < 256) atomicAdd(&ssq[(bn0+1)*8 + unit], r1[0]);
    }
}

// ---------------- K3: xq[p][b*8+u] = (Clin[co][n]+bias)*scl(b,u) ----------------
__global__ void k_xq2(const float* __restrict__ Clin, const float* __restrict__ bias,
                      const float* __restrict__ ssq, float* __restrict__ xq) {
    __shared__ float sT[32][257];
    __shared__ float sS[256];
    int p0 = blockIdx.x*32, tid = threadIdx.x;
    {
        float q = ssq[tid];
        sS[tid] = sqrtf(q) / (1.f + q);
    }
    __syncthreads();
    for (int r = 0; r < 32; ++r) {
        int e = r*256 + tid;
        int bu = e >> 5, pi = e & 31;
        int p = p0 + pi;
        int ch = p / 400, rr = p - ch*400;
        int unit = bu & 7, bn = bu >> 3;
        int co = unit*32 + ch;
        sT[pi][bu] = (Clin[(size_t)co*12800 + bn*400 + rr] + bias[co]) * sS[bu];
    }
    __syncthreads();
    for (int r = 0; r < 32; ++r)
        xq[(size_t)(p0+r)*256 + tid] = sT[r][tid];
}

// ---------------- K5: pass A — partial s_j; c = exp(bij)/cden (no max, |bij|<<1) ----------------
// grid (NBLK_A, 4): x = 64-p block, y = 40-os quarter. 256 thr = 8 g (5 os each) x 32 bq.
__global__ __launch_bounds__(256) void k_route_sj(const float* __restrict__ Wd,
        const float* __restrict__ xq, const float* __restrict__ bij,
        const float* __restrict__ cden, float* __restrict__ sjp, int uniform) {
    int tid = threadIdx.x;
    int bq = tid & 31, g = tid >> 5;
    int os0 = blockIdx.y*40 + g*5;
    int o0 = os0 >> 4, o1 = (os0 + 4) >> 4;   // 5-wide window spans 1 or 2 o's
    float rd0, rd1;
    if (uniform) { rd0 = 1.f/12800.f; rd1 = rd0; }
    else         { rd0 = 1.f/cden[o0]; rd1 = 1.f/cden[o1]; }
    float acc[5];
    #pragma unroll
    for (int i = 0; i < 5; ++i) acc[i] = 0.f;
    int p0 = blockIdx.x * 64;
    for (int p = p0; p < p0+64; ++p) {
        const float4* xr = (const float4*)(xq + (size_t)p*256 + bq*8);
        float4 xa = xr[0], xb = xr[1];
        float c0 = uniform ? rd0 : __expf(bij[p*10+o0]) * rd0;
        float c1 = (o1 == o0) ? c0 : (uniform ? rd1 : __expf(bij[p*10+o1]) * rd1);
        const float4* wr = (const float4*)(Wd + (size_t)p*1280 + os0*8);
        #pragma unroll
        for (int i = 0; i < 5; ++i) {
            float4 w0 = wr[i*2], w1 = wr[i*2+1];
            float uh = w0.x*xa.x + w0.y*xa.y + w0.z*xa.z + w0.w*xa.w
                     + w1.x*xb.x + w1.y*xb.y + w1.z*xb.z + w1.w*xb.w;
            int oi = (os0 + i) >> 4;
            acc[i] += (oi == o0 ? c0 : c1) * uh;
        }
    }
    float* outp = sjp + (size_t)blockIdx.x*5120 + bq*OSD + os0;
    #pragma unroll
    for (int i = 0; i < 5; ++i) outp[i] = acc[i];
}

// ---------------- K6: reduce partials -> s_j -> squash over O -> v (+out); zero cden ----------------
__global__ void k_reduce_squash(const float* __restrict__ sjp, float* __restrict__ v,
                                float* __restrict__ cden,
                                float* __restrict__ dout, int writeOut) {
    __shared__ float ss[640];
    __shared__ float sc[64];
    int tid = threadIdx.x;
    if (blockIdx.x == 0 && tid < 10) cden[tid] = 0.f;   // for next route_bij accumulation
    int e = blockIdx.x*640 + tid;
    float s = 0.f;
    for (int k = 0; k < NBLK_A; ++k) s += sjp[(size_t)k*5120 + e];
    ss[tid] = s;
    __syncthreads();
    if (tid < 64) {
        int bl = tid >> 4, sl = tid & 15;
        float msq = 0.f;
        #pragma unroll
        for (int o = 0; o < 10; ++o) { float t_ = ss[bl*160 + o*16 + sl]; msq += t_*t_; }
        sc[tid] = sqrtf(msq) / (1.f + msq);
    }
    __syncthreads();
    int bl = tid / 160, r = tid - bl*160, sl = r & 15;
    float val = ss[tid] * sc[bl*16 + sl];
    v[e] = val;
    if (writeOut) dout[e] = val;
}

// ---------------- K7: pass B — b_ij += mean_b sum_s u_hat*v ; accumulate cden[o] ----------------
__global__ __launch_bounds__(320) void k_route_bij(const float* __restrict__ Wd,
        const float* __restrict__ xq, const float* __restrict__ v,
        float* __restrict__ bij, float* __restrict__ cden) {
    __shared__ float sv[5120];
    __shared__ float sxq[32*260];
    __shared__ float red[320];
    int tid = threadIdx.x;
    int p0 = blockIdx.x*32;
    for (int e = tid; e < 5120; e += 320) sv[e] = v[e];
    for (int e = tid; e < 8192; e += 320) {
        int pl = e >> 8, bu = e & 255;
        sxq[pl*260 + bu] = xq[(size_t)(p0+pl)*256 + bu];
    }
    __syncthreads();
    int pl = tid / 10, o = tid - pl*10;
    int p = p0 + pl;
    const float4* wr = (const float4*)(Wd + (size_t)p*1280 + o*128);
    float4 wreg[32];
    #pragma unroll
    for (int i = 0; i < 32; ++i) wreg[i] = wr[i];
    float acc = 0.f;
    for (int bq = 0; bq < 32; ++bq) {
        float4 x0 = *(const float4*)&sxq[pl*260 + bq*8];
        float4 x1 = *(const float4*)&sxq[pl*260 + bq*8 + 4];
        #pragma unroll
        for (int sg = 0; sg < 4; ++sg) {
            float4 vs = *(const float4*)&sv[bq*160 + o*16 + sg*4];
            float vsv[4] = {vs.x, vs.y, vs.z, vs.w};
            #pragma unroll
            for (int s4 = 0; s4 < 4; ++s4) {
                int s = sg*4 + s4;
                float4 w0 = wreg[s*2], w1 = wreg[s*2+1];
                float uh = w0.x*x0.x + w0.y*x0.y + w0.z*x0.z + w0.w*x0.w
                         + w1.x*x1.x + w1.y*x1.y + w1.z*x1.z + w1.w*x1.w;
                acc += uh * vsv[s4];
            }
        }
    }
    float bn_ = bij[p*10 + o] + acc * (1.f/32.f);
    bij[p*10 + o] = bn_;
    red[tid] = __expf(bn_);
    __syncthreads();
    if (tid < 10) {
        float s_ = 0.f;
        #pragma unroll
        for (int j = 0; j < 32; ++j) s_ += red[tid + j*10];
        atomicAdd(&cden[tid], s_);
    }
}

extern "C" void kernel_launch(void* const* d_in, const int* in_sizes, int n_in,
                              void* d_out, int out_size, void* d_ws, size_t ws_size,
                              hipStream_t stream) {
    const float* x   = (const float*)d_in[0];
    const float* c1w = (const float*)d_in[1];
    const float* c1b = (const float*)d_in[2];
    const float* pw  = (const float*)d_in[3];
    const float* pb  = (const float*)d_in[4];
    const float* Wd  = (const float*)d_in[5];
    float* out = (float*)d_out;

    // workspace map (bytes)
    char* wsb = (char*)d_ws;
    _Float16* ht1 = (_Float16*)(wsb);                 // 12,845,056
    _Float16* ht2 = (_Float16*)(wsb + 12845056);      // 12,845,056
    _Float16* Wk1 = (_Float16*)(wsb + 25690112);      // 10,616,832
    _Float16* Wk2 = (_Float16*)(wsb + 36306944);      // 10,616,832
    float* Clin = (float*)(wsb + 46923776);           // 13,107,200
    char* tailb = wsb + 60030976;
    float* bij   = (float*)tailb;                     // 128000 f
    float* ssq   = bij + 128000;                      // 256 f
    float* cden  = ssq + 256;                         // 16 f
    float* vv    = cden + 16;                         // 5120 f
    // aliases over dead regions:
    float* xq  = (float*)(wsb);              // over ht planes (dead after GEMM); 13.1MB
    float* sjp = (float*)(wsb + 46923776);   // over Clin (dead after xq2); 200*5120 f

    hipMemsetAsync(Clin, 0, 13107200, stream);
    hipMemsetAsync(bij, 0, (128000 + 256)*sizeof(float), stream);  // bij + ssq

    k_prep_w<<<256, 256, 0, stream>>>(pw, Wk1, Wk2);
    k_conv1<<<dim3(32,16), 256, 0, stream>>>(x, c1w, c1b, ht1, ht2);
    k_prim_mfma<<<dim3(100,2,8), 512, 0, stream>>>(ht1, ht2, Wk1, Wk2, Clin);
    k_ssq<<<12800, 256, 0, stream>>>(Clin, pb, ssq);
    k_xq2<<<400, 256, 0, stream>>>(Clin, pb, ssq, xq);

    for (int it = 0; it < 3; ++it) {
        k_route_sj<<<dim3(NBLK_A,4), 256, 0, stream>>>(Wd, xq, bij, cden, sjp, it == 0 ? 1 : 0);
        k_reduce_squash<<<8, 640, 0, stream>>>(sjp, vv, cden, out, it == 2 ? 1 : 0);
        if (it < 2)
            k_route_bij<<<400, 320, 0, stream>>>(Wd, xq, vv, bij, cden);
    }
}

// Round 11
// 858.060 us; speedup vs baseline: 1.6909x; 1.1492x over previous
//
#include <hip/hip_runtime.h>
#include <math.h>

// ---- problem constants ----
static constexpr int PDIM = 12800;      // 32ch*400
static constexpr int OSD  = 160;        // 10*16
static constexpr int NBLK_A = 200;      // pass-A p-blocks (64 p each)

typedef _Float16 hv8  __attribute__((ext_vector_type(8)));
typedef float    f32x4 __attribute__((ext_vector_type(4)));

__device__ __forceinline__ void gload16(const void* g, void* l) {
    __builtin_amdgcn_global_load_lds(
        (const __attribute__((address_space(1))) void*)g,
        (__attribute__((address_space(3))) void*)l, 16, 0, 0);
}

// ---------------- K0: prim_w[co][ci][81] -> Wk1[k][co][ci] fp16 (single hi plane) ----------------
__global__ void k_prep_w(const float* __restrict__ w, _Float16* __restrict__ Wk1) {
    __shared__ float s[20736];          // one co-slice: [ci=256][k=81]
    int co = blockIdx.x, t = threadIdx.x;
    const float4* src = (const float4*)(w + (size_t)co*20736);
    float4* d4 = (float4*)s;
    for (int i = t; i < 5184; i += 256) d4[i] = src[i];
    __syncthreads();
    for (int k = 0; k < 81; ++k) {
        float val = s[t*81 + k];
        Wk1[(size_t)k*65536 + co*256 + t] = (_Float16)val;
    }
}

// ---------------- K1: conv1 + bias + relu -> ht planes [b][pos][co] fp16 x2 ----------------
__global__ void k_conv1(const float* __restrict__ x, const float* __restrict__ w,
                        const float* __restrict__ bias,
                        _Float16* __restrict__ ht1, _Float16* __restrict__ ht2) {
    __shared__ float sx[1296];
    __shared__ float sw[1296];
    int b = blockIdx.x, cog = blockIdx.y;
    int tid = threadIdx.x;
    for (int i = tid; i < 1296; i += 256) {
        sx[i] = x[b*1296 + i];
        sw[i] = w[cog*1296 + i];
    }
    __syncthreads();
    for (int pos = tid; pos < 784; pos += 256) {
        int y = pos / 28, xx = pos - y*28;
        float acc[16];
        #pragma unroll
        for (int c = 0; c < 16; ++c) acc[c] = 0.f;
        for (int ky = 0; ky < 9; ++ky) {
            #pragma unroll
            for (int kx = 0; kx < 9; ++kx) {
                float xv = sx[(y+ky)*36 + xx + kx];
                #pragma unroll
                for (int c = 0; c < 16; ++c)
                    acc[c] += xv * sw[c*81 + ky*9 + kx];
            }
        }
        #pragma unroll
        for (int c = 0; c < 16; ++c) {
            float r = acc[c] + bias[cog*16 + c];
            r = r > 0.f ? r : 0.f;
            _Float16 h1 = (_Float16)r;
            float q1 = r - (float)h1;
            _Float16 h2 = (_Float16)q1;
            size_t o = ((size_t)b*784 + pos)*256 + cog*16 + c;
            ht1[o] = h1; ht2[o] = h2;
        }
    }
}

// ---------------- K2: primary conv as 81 shifted GEMMs, fp16 split MFMA ----------------
// 2-PRODUCT SCHEME: C = w1*h1 + w1*h2 (dropped w2*h ~ 2^-11 random-sign, ~1e-4 rel on u).
// BM=128 BN=128 BK=32, 512 thr (8 waves 2x4, wave 64x32), dbuf 48KB -> 3 blocks/CU,
// __syncthreads 2-phase, ksplit=8 atomics. Only 16 MFMA + 3 gloads per step.
__global__ __launch_bounds__(512, 6) void k_prim_mfma(
        const _Float16* __restrict__ ht1, const _Float16* __restrict__ ht2,
        const _Float16* __restrict__ Wk1, float* __restrict__ Clin) {
    // per-buffer (halfs): A1 @0 (4096), B1 @4096, B2 @8192; BUF=12288 (24KB)
    __shared__ _Float16 lds[24576];
    const int t   = threadIdx.x;
    const int n0  = blockIdx.x * 128;
    const int co0 = blockIdx.y * 128;
    const int z   = blockIdx.z;
    const int klo = (z*81) >> 3, khi = ((z+1)*81) >> 3;
    const int NSTEP = (khi - klo) * 8;

    // staging precompute (source-pre-swizzled ci-group, LDS dest lane-linear)
    const int srow = t >> 2, slot = t & 3;
    const int g = slot ^ ((srow >> 1) & 3);
    const size_t aSrcOff = (size_t)(co0 + srow)*256 + g*8;
    const int n1 = n0 + srow;
    const int b1 = n1/400, rr1 = n1 - b1*400, y1 = rr1/20, x1 = rr1 - y1*20;
    const size_t bOff1 = ((size_t)b1*784 + y1*28 + x1)*256 + g*8;

    // compute-side: 8 waves 2x4, wave tile 64x32
    const int l = t & 63, w8 = t >> 6;
    const int wm = w8 >> 2, wn = w8 & 3;
    const int lm = l & 15, lk = l >> 4;
    int aoff[4], boff[2];
    #pragma unroll
    for (int i = 0; i < 4; ++i) {
        int ra = wm*64 + i*16 + lm;
        aoff[i] = ra*32 + ((lk ^ ((ra>>1)&3))*8);
    }
    #pragma unroll
    for (int j = 0; j < 2; ++j) {
        int rb = wn*32 + j*16 + lm;
        boff[j] = 4096 + rb*32 + ((lk ^ ((rb>>1)&3))*8);
    }

    f32x4 acc[4][2];
    #pragma unroll
    for (int i = 0; i < 4; ++i)
        #pragma unroll
        for (int j = 0; j < 2; ++j) { acc[i][j][0]=0.f; acc[i][j][1]=0.f; acc[i][j][2]=0.f; acc[i][j][3]=0.f; }

#define ASTAGE(S, LB) { int k_ = klo + ((S) >> 3), c_ = (S) & 7; \
        size_t ao = (size_t)k_*65536 + c_*32 + aSrcOff; \
        gload16(Wk1 + ao, (LB) + t*8); }

#define BGLOAD(S, LB) { int k_ = klo + ((S) >> 3), c_ = (S) & 7; \
        int spk_ = (k_/9)*28 + (k_ - (k_/9)*9); \
        size_t so = (size_t)spk_*256 + c_*32; \
        gload16(ht1 + bOff1 + so, (LB) + 4096 + t*8); \
        gload16(ht2 + bOff1 + so, (LB) + 8192 + t*8); }

#define COMPUTE(L) { hv8 a1[4]; \
        _Pragma("unroll") for (int mi = 0; mi < 4; ++mi) \
            a1[mi] = *(const hv8*)((L) + aoff[mi]); \
        _Pragma("unroll") for (int nj = 0; nj < 2; ++nj) { \
            hv8 q1 = *(const hv8*)((L) + boff[nj]); \
            hv8 q2 = *(const hv8*)((L) + 4096 + boff[nj]); \
            _Pragma("unroll") for (int mi = 0; mi < 4; ++mi) { \
                f32x4 c = acc[mi][nj]; \
                c = __builtin_amdgcn_mfma_f32_16x16x32_f16(a1[mi], q1, c, 0, 0, 0); \
                c = __builtin_amdgcn_mfma_f32_16x16x32_f16(a1[mi], q2, c, 0, 0, 0); \
                acc[mi][nj] = c; } } }

    // prologue: stage step 0 into buf0
    ASTAGE(0, lds); BGLOAD(0, lds);
    __syncthreads();

    for (int s = 0; s < NSTEP; ++s) {
        const int d = s & 1;
        _Float16* Lnext = lds + (d ? 0 : 12288);
        const _Float16* L = lds + (d ? 12288 : 0);
        if ((s + 1) < NSTEP) { ASTAGE(s+1, Lnext); BGLOAD(s+1, Lnext); }
        COMPUTE(L);
        __syncthreads();
    }

    // epilogue: atomic accumulate into Clin[co][n]
    #pragma unroll
    for (int mi = 0; mi < 4; ++mi) {
        #pragma unroll
        for (int nj = 0; nj < 2; ++nj) {
            int nn = n0 + wn*32 + nj*16 + lm;
            #pragma unroll
            for (int r = 0; r < 4; ++r) {
                int co = co0 + wm*64 + mi*16 + lk*4 + r;
                atomicAdd(&Clin[(size_t)co*12800 + nn], acc[mi][nj][r]);
            }
        }
    }
#undef ASTAGE
#undef BGLOAD
#undef COMPUTE
}

// ---------------- K2b: squared-norm partials per (b,u) from Clin+bias ----------------
__global__ void k_ssq(const float* __restrict__ Clin, const float* __restrict__ bias,
                      float* __restrict__ ssq) {
    __shared__ float r0[256], r1[256];
    int tid = threadIdx.x;
    int e = blockIdx.x*256 + tid;
    int co = e / 12800;
    int unit = co >> 5;
    float val = Clin[e] + bias[co];
    int n0b = (blockIdx.x % 50) * 256;
    int bn0 = n0b / 400;
    int nb  = (bn0+1)*400 - n0b;
    float v2 = val * val;
    bool hi = (tid >= nb);
    r0[tid] = hi ? 0.f : v2;
    r1[tid] = hi ? v2 : 0.f;
    __syncthreads();
    for (int st = 128; st > 0; st >>= 1) {
        if (tid < st) { r0[tid] += r0[tid+st]; r1[tid] += r1[tid+st]; }
        __syncthreads();
    }
    if (tid == 0) {
        atomicAdd(&ssq[bn0*8 + unit], r0[0]);
        if (nb < 256) atomicAdd(&ssq[(bn0+1)*8 + unit], r1[0]);
    }
}

// ---------------- K3: xq[p][b*8+u] = (Clin[co][n]+bias)*scl(b,u) ----------------
__global__ void k_xq2(const float* __restrict__ Clin, const float* __restrict__ bias,
                      const float* __restrict__ ssq, float* __restrict__ xq) {
    __shared__ float sT[32][257];
    __shared__ float sS[256];
    int p0 = blockIdx.x*32, tid = threadIdx.x;
    {
        float q = ssq[tid];
        sS[tid] = sqrtf(q) / (1.f + q);
    }
    __syncthreads();
    for (int r = 0; r < 32; ++r) {
        int e = r*256 + tid;
        int bu = e >> 5, pi = e & 31;
        int p = p0 + pi;
        int ch = p / 400, rr = p - ch*400;
        int unit = bu & 7, bn = bu >> 3;
        int co = unit*32 + ch;
        sT[pi][bu] = (Clin[(size_t)co*12800 + bn*400 + rr] + bias[co]) * sS[bu];
    }
    __syncthreads();
    for (int r = 0; r < 32; ++r)
        xq[(size_t)(p0+r)*256 + tid] = sT[r][tid];
}

// ---------------- K5: pass A — partial s_j; c = exp(bij)/cden (no max, |bij|<<1) ----------------
// grid (NBLK_A, 4): x = 64-p block, y = 40-os quarter. 256 thr = 8 g (5 os each) x 32 bq.
__global__ __launch_bounds__(256) void k_route_sj(const float* __restrict__ Wd,
        const float* __restrict__ xq, const float* __restrict__ bij,
        const float* __restrict__ cden, float* __restrict__ sjp, int uniform) {
    int tid = threadIdx.x;
    int bq = tid & 31, g = tid >> 5;
    int os0 = blockIdx.y*40 + g*5;
    int o0 = os0 >> 4, o1 = (os0 + 4) >> 4;   // 5-wide window spans 1 or 2 o's
    float rd0, rd1;
    if (uniform) { rd0 = 1.f/12800.f; rd1 = rd0; }
    else         { rd0 = 1.f/cden[o0]; rd1 = 1.f/cden[o1]; }
    float acc[5];
    #pragma unroll
    for (int i = 0; i < 5; ++i) acc[i] = 0.f;
    int p0 = blockIdx.x * 64;
    for (int p = p0; p < p0+64; ++p) {
        const float4* xr = (const float4*)(xq + (size_t)p*256 + bq*8);
        float4 xa = xr[0], xb = xr[1];
        float c0 = uniform ? rd0 : __expf(bij[p*10+o0]) * rd0;
        float c1 = (o1 == o0) ? c0 : (uniform ? rd1 : __expf(bij[p*10+o1]) * rd1);
        const float4* wr = (const float4*)(Wd + (size_t)p*1280 + os0*8);
        #pragma unroll
        for (int i = 0; i < 5; ++i) {
            float4 w0 = wr[i*2], w1 = wr[i*2+1];
            float uh = w0.x*xa.x + w0.y*xa.y + w0.z*xa.z + w0.w*xa.w
                     + w1.x*xb.x + w1.y*xb.y + w1.z*xb.z + w1.w*xb.w;
            int oi = (os0 + i) >> 4;
            acc[i] += (oi == o0 ? c0 : c1) * uh;
        }
    }
    float* outp = sjp + (size_t)blockIdx.x*5120 + bq*OSD + os0;
    #pragma unroll
    for (int i = 0; i < 5; ++i) outp[i] = acc[i];
}

// ---------------- K6: reduce partials -> s_j -> squash over O -> v (+out); zero cden ----------------
__global__ void k_reduce_squash(const float* __restrict__ sjp, float* __restrict__ v,
                                float* __restrict__ cden,
                                float* __restrict__ dout, int writeOut) {
    __shared__ float ss[640];
    __shared__ float sc[64];
    int tid = threadIdx.x;
    if (blockIdx.x == 0 && tid < 10) cden[tid] = 0.f;   // for next route_bij accumulation
    int e = blockIdx.x*640 + tid;
    float s = 0.f;
    for (int k = 0; k < NBLK_A; ++k) s += sjp[(size_t)k*5120 + e];
    ss[tid] = s;
    __syncthreads();
    if (tid < 64) {
        int bl = tid >> 4, sl = tid & 15;
        float msq = 0.f;
        #pragma unroll
        for (int o = 0; o < 10; ++o) { float t_ = ss[bl*160 + o*16 + sl]; msq += t_*t_; }
        sc[tid] = sqrtf(msq) / (1.f + msq);
    }
    __syncthreads();
    int bl = tid / 160, r = tid - bl*160, sl = r & 15;
    float val = ss[tid] * sc[bl*16 + sl];
    v[e] = val;
    if (writeOut) dout[e] = val;
}

// ---------------- K7: pass B — b_ij += mean_b sum_s u_hat*v ; accumulate cden[o] ----------------
__global__ __launch_bounds__(320) void k_route_bij(const float* __restrict__ Wd,
        const float* __restrict__ xq, const float* __restrict__ v,
        float* __restrict__ bij, float* __restrict__ cden) {
    __shared__ float sv[5120];
    __shared__ float sxq[32*260];
    __shared__ float red[320];
    int tid = threadIdx.x;
    int p0 = blockIdx.x*32;
    for (int e = tid; e < 5120; e += 320) sv[e] = v[e];
    for (int e = tid; e < 8192; e += 320) {
        int pl = e >> 8, bu = e & 255;
        sxq[pl*260 + bu] = xq[(size_t)(p0+pl)*256 + bu];
    }
    __syncthreads();
    int pl = tid / 10, o = tid - pl*10;
    int p = p0 + pl;
    const float4* wr = (const float4*)(Wd + (size_t)p*1280 + o*128);
    float4 wreg[32];
    #pragma unroll
    for (int i = 0; i < 32; ++i) wreg[i] = wr[i];
    float acc = 0.f;
    for (int bq = 0; bq < 32; ++bq) {
        float4 x0 = *(const float4*)&sxq[pl*260 + bq*8];
        float4 x1 = *(const float4*)&sxq[pl*260 + bq*8 + 4];
        #pragma unroll
        for (int sg = 0; sg < 4; ++sg) {
            float4 vs = *(const float4*)&sv[bq*160 + o*16 + sg*4];
            float vsv[4] = {vs.x, vs.y, vs.z, vs.w};
            #pragma unroll
            for (int s4 = 0; s4 < 4; ++s4) {
                int s = sg*4 + s4;
                float4 w0 = wreg[s*2], w1 = wreg[s*2+1];
                float uh = w0.x*x0.x + w0.y*x0.y + w0.z*x0.z + w0.w*x0.w
                         + w1.x*x1.x + w1.y*x1.y + w1.z*x1.z + w1.w*x1.w;
                acc += uh * vsv[s4];
            }
        }
    }
    float bn_ = bij[p*10 + o] + acc * (1.f/32.f);
    bij[p*10 + o] = bn_;
    red[tid] = __expf(bn_);
    __syncthreads();
    if (tid < 10) {
        float s_ = 0.f;
        #pragma unroll
        for (int j = 0; j < 32; ++j) s_ += red[tid + j*10];
        atomicAdd(&cden[tid], s_);
    }
}

extern "C" void kernel_launch(void* const* d_in, const int* in_sizes, int n_in,
                              void* d_out, int out_size, void* d_ws, size_t ws_size,
                              hipStream_t stream) {
    const float* x   = (const float*)d_in[0];
    const float* c1w = (const float*)d_in[1];
    const float* c1b = (const float*)d_in[2];
    const float* pw  = (const float*)d_in[3];
    const float* pb  = (const float*)d_in[4];
    const float* Wd  = (const float*)d_in[5];
    float* out = (float*)d_out;

    // workspace map (bytes)
    char* wsb = (char*)d_ws;
    _Float16* ht1 = (_Float16*)(wsb);                 // 12,845,056
    _Float16* ht2 = (_Float16*)(wsb + 12845056);      // 12,845,056
    _Float16* Wk1 = (_Float16*)(wsb + 25690112);      // 10,616,832
    float* Clin = (float*)(wsb + 46923776);           // 13,107,200
    char* tailb = wsb + 60030976;
    float* bij   = (float*)tailb;                     // 128000 f
    float* ssq   = bij + 128000;                      // 256 f
    float* cden  = ssq + 256;                         // 16 f
    float* vv    = cden + 16;                         // 5120 f
    // aliases over dead regions:
    float* xq  = (float*)(wsb);              // over ht planes (dead after GEMM); 13.1MB
    float* sjp = (float*)(wsb + 46923776);   // over Clin (dead after xq2); 200*5120 f

    hipMemsetAsync(Clin, 0, 13107200, stream);
    hipMemsetAsync(bij, 0, (128000 + 256)*sizeof(float), stream);  // bij + ssq

    k_prep_w<<<256, 256, 0, stream>>>(pw, Wk1);
    k_conv1<<<dim3(32,16), 256, 0, stream>>>(x, c1w, c1b, ht1, ht2);
    k_prim_mfma<<<dim3(100,2,8), 512, 0, stream>>>(ht1, ht2, Wk1, Clin);
    k_ssq<<<12800, 256, 0, stream>>>(Clin, pb, ssq);
    k_xq2<<<400, 256, 0, stream>>>(Clin, pb, ssq, xq);

    for (int it = 0; it < 3; ++it) {
        k_route_sj<<<dim3(NBLK_A,4), 256, 0, stream>>>(Wd, xq, bij, cden, sjp, it == 0 ? 1 : 0);
        k_reduce_squash<<<8, 640, 0, stream>>>(sjp, vv, cden, out, it == 2 ? 1 : 0);
        if (it < 2)
            k_route_bij<<<400, 320, 0, stream>>>(Wd, xq, vv, bij, cden);
    }
}

// Round 12
// 782.408 us; speedup vs baseline: 1.8544x; 1.0967x over previous
//
#include <hip/hip_runtime.h>
#include <math.h>

// ---- problem constants ----
static constexpr int PDIM = 12800;      // 32ch*400
static constexpr int OSD  = 160;        // 10*16
static constexpr int NBLK_A = 200;      // pass-A p-blocks (64 p each)

typedef _Float16 hv8  __attribute__((ext_vector_type(8)));
typedef float    f32x4 __attribute__((ext_vector_type(4)));

__device__ __forceinline__ void gload16(const void* g, void* l) {
    __builtin_amdgcn_global_load_lds(
        (const __attribute__((address_space(1))) void*)g,
        (__attribute__((address_space(3))) void*)l, 16, 0, 0);
}

// ---------------- K0: prim_w[co][ci][81] -> Wk1[k][co][ci] fp16 ----------------
__global__ void k_prep_w(const float* __restrict__ w, _Float16* __restrict__ Wk1) {
    __shared__ float s[20736];          // one co-slice: [ci=256][k=81]
    int co = blockIdx.x, t = threadIdx.x;
    const float4* src = (const float4*)(w + (size_t)co*20736);
    float4* d4 = (float4*)s;
    for (int i = t; i < 5184; i += 256) d4[i] = src[i];
    __syncthreads();
    for (int k = 0; k < 81; ++k)
        Wk1[(size_t)k*65536 + co*256 + t] = (_Float16)s[t*81 + k];
}

// ---------------- K1: conv1 + bias + relu -> ht1[b][pos][co] fp16 ----------------
__global__ void k_conv1(const float* __restrict__ x, const float* __restrict__ w,
                        const float* __restrict__ bias, _Float16* __restrict__ ht1) {
    __shared__ float sx[1296];
    __shared__ float sw[1296];
    int b = blockIdx.x, cog = blockIdx.y;
    int tid = threadIdx.x;
    for (int i = tid; i < 1296; i += 256) {
        sx[i] = x[b*1296 + i];
        sw[i] = w[cog*1296 + i];
    }
    __syncthreads();
    for (int pos = tid; pos < 784; pos += 256) {
        int y = pos / 28, xx = pos - y*28;
        float acc[16];
        #pragma unroll
        for (int c = 0; c < 16; ++c) acc[c] = 0.f;
        for (int ky = 0; ky < 9; ++ky) {
            #pragma unroll
            for (int kx = 0; kx < 9; ++kx) {
                float xv = sx[(y+ky)*36 + xx + kx];
                #pragma unroll
                for (int c = 0; c < 16; ++c)
                    acc[c] += xv * sw[c*81 + ky*9 + kx];
            }
        }
        #pragma unroll
        for (int c = 0; c < 16; ++c) {
            float r = acc[c] + bias[cog*16 + c];
            r = r > 0.f ? r : 0.f;
            ht1[((size_t)b*784 + pos)*256 + cog*16 + c] = (_Float16)r;
        }
    }
}

// ---------------- K2: primary conv as 81 shifted GEMMs, pure fp16 MFMA ----------------
// 1-PRODUCT: C = fp16(w)*fp16(h). Validated error model: each ~2^-11 random-sign dropped
// class adds ~4e-12 absmax (threshold 4.95e-11). BM=128 BN=128 BK=32, 512 thr (8 waves
// 2x4, wave 64x32), dbuf 32KB -> 4 blocks/CU, __syncthreads 2-phase, ksplit=8 atomics.
__global__ __launch_bounds__(512, 8) void k_prim_mfma(
        const _Float16* __restrict__ ht1, const _Float16* __restrict__ Wk1,
        float* __restrict__ Clin) {
    // per-buffer (halfs): A @0 (4096), B @4096; BUF=8192 (16KB)
    __shared__ _Float16 lds[16384];
    const int t   = threadIdx.x;
    const int n0  = blockIdx.x * 128;
    const int co0 = blockIdx.y * 128;
    const int z   = blockIdx.z;
    const int klo = (z*81) >> 3, khi = ((z+1)*81) >> 3;
    const int NSTEP = (khi - klo) * 8;

    // staging precompute (source-pre-swizzled ci-group, LDS dest lane-linear)
    const int srow = t >> 2, slot = t & 3;
    const int g = slot ^ ((srow >> 1) & 3);
    const size_t aSrcOff = (size_t)(co0 + srow)*256 + g*8;
    const int n1 = n0 + srow;
    const int b1 = n1/400, rr1 = n1 - b1*400, y1 = rr1/20, x1 = rr1 - y1*20;
    const size_t bOff1 = ((size_t)b1*784 + y1*28 + x1)*256 + g*8;

    // compute-side: 8 waves 2x4, wave tile 64x32
    const int l = t & 63, w8 = t >> 6;
    const int wm = w8 >> 2, wn = w8 & 3;
    const int lm = l & 15, lk = l >> 4;
    int aoff[4], boff[2];
    #pragma unroll
    for (int i = 0; i < 4; ++i) {
        int ra = wm*64 + i*16 + lm;
        aoff[i] = ra*32 + ((lk ^ ((ra>>1)&3))*8);
    }
    #pragma unroll
    for (int j = 0; j < 2; ++j) {
        int rb = wn*32 + j*16 + lm;
        boff[j] = 4096 + rb*32 + ((lk ^ ((rb>>1)&3))*8);
    }

    f32x4 acc[4][2];
    #pragma unroll
    for (int i = 0; i < 4; ++i)
        #pragma unroll
        for (int j = 0; j < 2; ++j) { acc[i][j][0]=0.f; acc[i][j][1]=0.f; acc[i][j][2]=0.f; acc[i][j][3]=0.f; }

#define STAGE(S, LB) { int k_ = klo + ((S) >> 3), c_ = (S) & 7; \
        size_t ao = (size_t)k_*65536 + c_*32 + aSrcOff; \
        gload16(Wk1 + ao, (LB) + t*8); \
        int spk_ = (k_/9)*28 + (k_ - (k_/9)*9); \
        size_t so = (size_t)spk_*256 + c_*32; \
        gload16(ht1 + bOff1 + so, (LB) + 4096 + t*8); }

#define COMPUTE(L) { hv8 a1[4]; \
        _Pragma("unroll") for (int mi = 0; mi < 4; ++mi) \
            a1[mi] = *(const hv8*)((L) + aoff[mi]); \
        _Pragma("unroll") for (int nj = 0; nj < 2; ++nj) { \
            hv8 q1 = *(const hv8*)((L) + boff[nj]); \
            _Pragma("unroll") for (int mi = 0; mi < 4; ++mi) \
                acc[mi][nj] = __builtin_amdgcn_mfma_f32_16x16x32_f16(a1[mi], q1, acc[mi][nj], 0, 0, 0); } }

    // prologue: stage step 0 into buf0
    STAGE(0, lds);
    __syncthreads();

    for (int s = 0; s < NSTEP; ++s) {
        const int d = s & 1;
        _Float16* Lnext = lds + (d ? 0 : 8192);
        const _Float16* L = lds + (d ? 8192 : 0);
        if ((s + 1) < NSTEP) STAGE(s+1, Lnext);
        COMPUTE(L);
        __syncthreads();
    }

    // epilogue: atomic accumulate into Clin[co][n]
    #pragma unroll
    for (int mi = 0; mi < 4; ++mi) {
        #pragma unroll
        for (int nj = 0; nj < 2; ++nj) {
            int nn = n0 + wn*32 + nj*16 + lm;
            #pragma unroll
            for (int r = 0; r < 4; ++r) {
                int co = co0 + wm*64 + mi*16 + lk*4 + r;
                atomicAdd(&Clin[(size_t)co*12800 + nn], acc[mi][nj][r]);
            }
        }
    }
#undef STAGE
#undef COMPUTE
}

// ---------------- K2b: squared-norm partials per (b,u) from Clin+bias ----------------
__global__ void k_ssq(const float* __restrict__ Clin, const float* __restrict__ bias,
                      float* __restrict__ ssq) {
    __shared__ float r0[256], r1[256];
    int tid = threadIdx.x;
    int e = blockIdx.x*256 + tid;
    int co = e / 12800;
    int unit = co >> 5;
    float val = Clin[e] + bias[co];
    int n0b = (blockIdx.x % 50) * 256;
    int bn0 = n0b / 400;
    int nb  = (bn0+1)*400 - n0b;
    float v2 = val * val;
    bool hi = (tid >= nb);
    r0[tid] = hi ? 0.f : v2;
    r1[tid] = hi ? v2 : 0.f;
    __syncthreads();
    for (int st = 128; st > 0; st >>= 1) {
        if (tid < st) { r0[tid] += r0[tid+st]; r1[tid] += r1[tid+st]; }
        __syncthreads();
    }
    if (tid == 0) {
        atomicAdd(&ssq[bn0*8 + unit], r0[0]);
        if (nb < 256) atomicAdd(&ssq[(bn0+1)*8 + unit], r1[0]);
    }
}

// ---------------- K3: xq[p][b*8+u] = (Clin[co][n]+bias)*scl(b,u) ----------------
__global__ void k_xq2(const float* __restrict__ Clin, const float* __restrict__ bias,
                      const float* __restrict__ ssq, float* __restrict__ xq) {
    __shared__ float sT[32][257];
    __shared__ float sS[256];
    int p0 = blockIdx.x*32, tid = threadIdx.x;
    {
        float q = ssq[tid];
        sS[tid] = sqrtf(q) / (1.f + q);
    }
    __syncthreads();
    for (int r = 0; r < 32; ++r) {
        int e = r*256 + tid;
        int bu = e >> 5, pi = e & 31;
        int p = p0 + pi;
        int ch = p / 400, rr = p - ch*400;
        int unit = bu & 7, bn = bu >> 3;
        int co = unit*32 + ch;
        sT[pi][bu] = (Clin[(size_t)co*12800 + bn*400 + rr] + bias[co]) * sS[bu];
    }
    __syncthreads();
    for (int r = 0; r < 32; ++r)
        xq[(size_t)(p0+r)*256 + tid] = sT[r][tid];
}

// ---------------- K5: pass A — partial s_j; c = exp(bij)/cden (no max, |bij|<<1) ----------------
// grid (NBLK_A, 4): x = 64-p block, y = 40-os quarter. 256 thr = 8 g (5 os each) x 32 bq.
__global__ __launch_bounds__(256) void k_route_sj(const float* __restrict__ Wd,
        const float* __restrict__ xq, const float* __restrict__ bij,
        const float* __restrict__ cden, float* __restrict__ sjp, int uniform) {
    int tid = threadIdx.x;
    int bq = tid & 31, g = tid >> 5;
    int os0 = blockIdx.y*40 + g*5;
    int o0 = os0 >> 4, o1 = (os0 + 4) >> 4;   // 5-wide window spans 1 or 2 o's
    float rd0, rd1;
    if (uniform) { rd0 = 1.f/12800.f; rd1 = rd0; }
    else         { rd0 = 1.f/cden[o0]; rd1 = 1.f/cden[o1]; }
    float acc[5];
    #pragma unroll
    for (int i = 0; i < 5; ++i) acc[i] = 0.f;
    int p0 = blockIdx.x * 64;
    for (int p = p0; p < p0+64; ++p) {
        const float4* xr = (const float4*)(xq + (size_t)p*256 + bq*8);
        float4 xa = xr[0], xb = xr[1];
        float c0 = uniform ? rd0 : __expf(bij[p*10+o0]) * rd0;
        float c1 = (o1 == o0) ? c0 : (uniform ? rd1 : __expf(bij[p*10+o1]) * rd1);
        const float4* wr = (const float4*)(Wd + (size_t)p*1280 + os0*8);
        #pragma unroll
        for (int i = 0; i < 5; ++i) {
            float4 w0 = wr[i*2], w1 = wr[i*2+1];
            float uh = w0.x*xa.x + w0.y*xa.y + w0.z*xa.z + w0.w*xa.w
                     + w1.x*xb.x + w1.y*xb.y + w1.z*xb.z + w1.w*xb.w;
            int oi = (os0 + i) >> 4;
            acc[i] += (oi == o0 ? c0 : c1) * uh;
        }
    }
    float* outp = sjp + (size_t)blockIdx.x*5120 + bq*OSD + os0;
    #pragma unroll
    for (int i = 0; i < 5; ++i) outp[i] = acc[i];
}

// ---------------- K6: reduce partials -> s_j -> squash over O -> v (+out); zero cden ----------------
// grid 32 (one b each), 640 thr = 4 k-quarters x 160 e. Serial chain 200 -> 50.
__global__ void k_reduce_squash(const float* __restrict__ sjp, float* __restrict__ v,
                                float* __restrict__ cden,
                                float* __restrict__ dout, int writeOut) {
    __shared__ float ps[640];
    __shared__ float sc[16];
    int tid = threadIdx.x;
    int b = blockIdx.x;
    if (b == 0 && tid < 10) cden[tid] = 0.f;   // for next route_bij accumulation
    int q = tid / 160, el = tid - q*160;
    float s = 0.f;
    for (int k = q; k < NBLK_A; k += 4) s += sjp[(size_t)k*5120 + b*160 + el];
    ps[tid] = s;
    __syncthreads();
    float sfull = 0.f;
    if (tid < 160) {
        sfull = ps[tid] + ps[160+tid] + ps[320+tid] + ps[480+tid];
        ps[tid] = sfull;
    }
    __syncthreads();
    if (tid < 16) {
        float msq = 0.f;
        #pragma unroll
        for (int o = 0; o < 10; ++o) { float t_ = ps[o*16 + tid]; msq += t_*t_; }
        sc[tid] = sqrtf(msq) / (1.f + msq);
    }
    __syncthreads();
    if (tid < 160) {
        float val = sfull * sc[tid & 15];
        int e = b*160 + tid;
        v[e] = val;
        if (writeOut) dout[e] = val;
    }
}

// ---------------- K7: pass B — b_ij += mean_b sum_s u_hat*v ; accumulate cden[o] ----------------
// wreg split into two 16-float4 s-passes (VGPR ~105 vs 168 -> higher occupancy).
__global__ __launch_bounds__(320) void k_route_bij(const float* __restrict__ Wd,
        const float* __restrict__ xq, const float* __restrict__ v,
        float* __restrict__ bij, float* __restrict__ cden) {
    __shared__ float sv[5120];
    __shared__ float sxq[32*260];
    __shared__ float red[320];
    int tid = threadIdx.x;
    int p0 = blockIdx.x*32;
    for (int e = tid; e < 5120; e += 320) sv[e] = v[e];
    for (int e = tid; e < 8192; e += 320) {
        int pl = e >> 8, bu = e & 255;
        sxq[pl*260 + bu] = xq[(size_t)(p0+pl)*256 + bu];
    }
    __syncthreads();
    int pl = tid / 10, o = tid - pl*10;
    int p = p0 + pl;
    const float4* wr = (const float4*)(Wd + (size_t)p*1280 + o*128);
    float acc = 0.f;
    #pragma unroll
    for (int hf = 0; hf < 2; ++hf) {
        float4 wreg[16];
        #pragma unroll
        for (int i = 0; i < 16; ++i) wreg[i] = wr[hf*16 + i];
        for (int bq = 0; bq < 32; ++bq) {
            float4 x0 = *(const float4*)&sxq[pl*260 + bq*8];
            float4 x1 = *(const float4*)&sxq[pl*260 + bq*8 + 4];
            #pragma unroll
            for (int sg = 0; sg < 2; ++sg) {
                float4 vs = *(const float4*)&sv[bq*160 + o*16 + hf*8 + sg*4];
                float vsv[4] = {vs.x, vs.y, vs.z, vs.w};
                #pragma unroll
                for (int s4 = 0; s4 < 4; ++s4) {
                    int si = sg*4 + s4;
                    float4 w0 = wreg[si*2], w1 = wreg[si*2+1];
                    float uh = w0.x*x0.x + w0.y*x0.y + w0.z*x0.z + w0.w*x0.w
                             + w1.x*x1.x + w1.y*x1.y + w1.z*x1.z + w1.w*x1.w;
                    acc += uh * vsv[s4];
                }
            }
        }
    }
    float bn_ = bij[p*10 + o] + acc * (1.f/32.f);
    bij[p*10 + o] = bn_;
    red[tid] = __expf(bn_);
    __syncthreads();
    if (tid < 10) {
        float s_ = 0.f;
        #pragma unroll
        for (int j = 0; j < 32; ++j) s_ += red[tid + j*10];
        atomicAdd(&cden[tid], s_);
    }
}

extern "C" void kernel_launch(void* const* d_in, const int* in_sizes, int n_in,
                              void* d_out, int out_size, void* d_ws, size_t ws_size,
                              hipStream_t stream) {
    const float* x   = (const float*)d_in[0];
    const float* c1w = (const float*)d_in[1];
    const float* c1b = (const float*)d_in[2];
    const float* pw  = (const float*)d_in[3];
    const float* pb  = (const float*)d_in[4];
    const float* Wd  = (const float*)d_in[5];
    float* out = (float*)d_out;

    // workspace map (bytes)
    char* wsb = (char*)d_ws;
    _Float16* ht1 = (_Float16*)(wsb);                 // 12,845,056
    _Float16* Wk1 = (_Float16*)(wsb + 12845056);      // 10,616,832
    float* Clin = (float*)(wsb + 23461888);           // 13,107,200
    char* tailb = wsb + 36569088;
    float* bij   = (float*)tailb;                     // 128000 f
    float* ssq   = bij + 128000;                      // 256 f
    float* cden  = ssq + 256;                         // 16 f
    float* vv    = cden + 16;                         // 5120 f
    // aliases over dead regions:
    float* xq  = (float*)(wsb);              // 13.1MB over ht1+head of Wk1 (dead after GEMM)
    float* sjp = (float*)(wsb + 23461888);   // over Clin (dead after xq2); 200*5120 f

    hipMemsetAsync(Clin, 0, 13107200, stream);
    hipMemsetAsync(bij, 0, (128000 + 256)*sizeof(float), stream);  // bij + ssq

    k_prep_w<<<256, 256, 0, stream>>>(pw, Wk1);
    k_conv1<<<dim3(32,16), 256, 0, stream>>>(x, c1w, c1b, ht1);
    k_prim_mfma<<<dim3(100,2,8), 512, 0, stream>>>(ht1, Wk1, Clin);
    k_ssq<<<12800, 256, 0, stream>>>(Clin, pb, ssq);
    k_xq2<<<400, 256, 0, stream>>>(Clin, pb, ssq, xq);

    for (int it = 0; it < 3; ++it) {
        k_route_sj<<<dim3(NBLK_A,4), 256, 0, stream>>>(Wd, xq, bij, cden, sjp, it == 0 ? 1 : 0);
        k_reduce_squash<<<32, 640, 0, stream>>>(sjp, vv, cden, out, it == 2 ? 1 : 0);
        if (it < 2)
            k_route_bij<<<400, 320, 0, stream>>>(Wd, xq, vv, bij, cden);
    }
}

// Round 13
// 761.588 us; speedup vs baseline: 1.9051x; 1.0273x over previous
//
#include <hip/hip_runtime.h>
#include <math.h>

// ---- problem constants ----
static constexpr int PDIM = 12800;      // 32ch*400
static constexpr int OSD  = 160;        // 10*16
static constexpr int NBLK_A = 200;      // pass-A p-blocks (64 p each)

typedef _Float16 hv8  __attribute__((ext_vector_type(8)));
typedef _Float16 hv4  __attribute__((ext_vector_type(4)));
typedef float    f32x4 __attribute__((ext_vector_type(4)));

__device__ __forceinline__ void gload16(const void* g, void* l) {
    __builtin_amdgcn_global_load_lds(
        (const __attribute__((address_space(1))) void*)g,
        (__attribute__((address_space(3))) void*)l, 16, 0, 0);
}

// ---------------- K0: prim_w[co][ci][81] -> Wk1[k][co][ci] fp16 ----------------
__global__ void k_prep_w(const float* __restrict__ w, _Float16* __restrict__ Wk1) {
    __shared__ float s[20736];          // one co-slice: [ci=256][k=81]
    int co = blockIdx.x, t = threadIdx.x;
    const float4* src = (const float4*)(w + (size_t)co*20736);
    float4* d4 = (float4*)s;
    for (int i = t; i < 5184; i += 256) d4[i] = src[i];
    __syncthreads();
    for (int k = 0; k < 81; ++k)
        Wk1[(size_t)k*65536 + co*256 + t] = (_Float16)s[t*81 + k];
}

// ---------------- K0b: Wd fp32 -> Wh fp16 (same [P][O][S][U] layout) ----------------
__global__ void k_prep_wd(const float* __restrict__ Wd, _Float16* __restrict__ Wh) {
    size_t i = ((size_t)blockIdx.x*256 + threadIdx.x) * 4;   // 16,384,000 total floats
    float4 v = *(const float4*)(Wd + i);
    hv4 h;
    h[0] = (_Float16)v.x; h[1] = (_Float16)v.y;
    h[2] = (_Float16)v.z; h[3] = (_Float16)v.w;
    *(hv4*)(Wh + i) = h;
}

// ---------------- K1: conv1 + bias + relu -> ht1[b][pos][co] fp16 ----------------
__global__ void k_conv1(const float* __restrict__ x, const float* __restrict__ w,
                        const float* __restrict__ bias, _Float16* __restrict__ ht1) {
    __shared__ float sx[1296];
    __shared__ float sw[1296];
    int b = blockIdx.x, cog = blockIdx.y;
    int tid = threadIdx.x;
    for (int i = tid; i < 1296; i += 256) {
        sx[i] = x[b*1296 + i];
        sw[i] = w[cog*1296 + i];
    }
    __syncthreads();
    for (int pos = tid; pos < 784; pos += 256) {
        int y = pos / 28, xx = pos - y*28;
        float acc[16];
        #pragma unroll
        for (int c = 0; c < 16; ++c) acc[c] = 0.f;
        for (int ky = 0; ky < 9; ++ky) {
            #pragma unroll
            for (int kx = 0; kx < 9; ++kx) {
                float xv = sx[(y+ky)*36 + xx + kx];
                #pragma unroll
                for (int c = 0; c < 16; ++c)
                    acc[c] += xv * sw[c*81 + ky*9 + kx];
            }
        }
        #pragma unroll
        for (int c = 0; c < 16; ++c) {
            float r = acc[c] + bias[cog*16 + c];
            r = r > 0.f ? r : 0.f;
            ht1[((size_t)b*784 + pos)*256 + cog*16 + c] = (_Float16)r;
        }
    }
}

// ---------------- K2: primary conv as 81 shifted GEMMs, pure fp16 MFMA ----------------
// 1-PRODUCT: C = fp16(w)*fp16(h). BM=128 BN=128 BK=32, 512 thr (8 waves 2x4, wave 64x32),
// dbuf 32KB -> 4 blocks/CU, __syncthreads 2-phase, ksplit=8 atomics. (Round-12, frozen.)
__global__ __launch_bounds__(512, 8) void k_prim_mfma(
        const _Float16* __restrict__ ht1, const _Float16* __restrict__ Wk1,
        float* __restrict__ Clin) {
    // per-buffer (halfs): A @0 (4096), B @4096; BUF=8192 (16KB)
    __shared__ _Float16 lds[16384];
    const int t   = threadIdx.x;
    const int n0  = blockIdx.x * 128;
    const int co0 = blockIdx.y * 128;
    const int z   = blockIdx.z;
    const int klo = (z*81) >> 3, khi = ((z+1)*81) >> 3;
    const int NSTEP = (khi - klo) * 8;

    const int srow = t >> 2, slot = t & 3;
    const int g = slot ^ ((srow >> 1) & 3);
    const size_t aSrcOff = (size_t)(co0 + srow)*256 + g*8;
    const int n1 = n0 + srow;
    const int b1 = n1/400, rr1 = n1 - b1*400, y1 = rr1/20, x1 = rr1 - y1*20;
    const size_t bOff1 = ((size_t)b1*784 + y1*28 + x1)*256 + g*8;

    const int l = t & 63, w8 = t >> 6;
    const int wm = w8 >> 2, wn = w8 & 3;
    const int lm = l & 15, lk = l >> 4;
    int aoff[4], boff[2];
    #pragma unroll
    for (int i = 0; i < 4; ++i) {
        int ra = wm*64 + i*16 + lm;
        aoff[i] = ra*32 + ((lk ^ ((ra>>1)&3))*8);
    }
    #pragma unroll
    for (int j = 0; j < 2; ++j) {
        int rb = wn*32 + j*16 + lm;
        boff[j] = 4096 + rb*32 + ((lk ^ ((rb>>1)&3))*8);
    }

    f32x4 acc[4][2];
    #pragma unroll
    for (int i = 0; i < 4; ++i)
        #pragma unroll
        for (int j = 0; j < 2; ++j) { acc[i][j][0]=0.f; acc[i][j][1]=0.f; acc[i][j][2]=0.f; acc[i][j][3]=0.f; }

#define STAGE(S, LB) { int k_ = klo + ((S) >> 3), c_ = (S) & 7; \
        size_t ao = (size_t)k_*65536 + c_*32 + aSrcOff; \
        gload16(Wk1 + ao, (LB) + t*8); \
        int spk_ = (k_/9)*28 + (k_ - (k_/9)*9); \
        size_t so = (size_t)spk_*256 + c_*32; \
        gload16(ht1 + bOff1 + so, (LB) + 4096 + t*8); }

#define COMPUTE(L) { hv8 a1[4]; \
        _Pragma("unroll") for (int mi = 0; mi < 4; ++mi) \
            a1[mi] = *(const hv8*)((L) + aoff[mi]); \
        _Pragma("unroll") for (int nj = 0; nj < 2; ++nj) { \
            hv8 q1 = *(const hv8*)((L) + boff[nj]); \
            _Pragma("unroll") for (int mi = 0; mi < 4; ++mi) \
                acc[mi][nj] = __builtin_amdgcn_mfma_f32_16x16x32_f16(a1[mi], q1, acc[mi][nj], 0, 0, 0); } }

    STAGE(0, lds);
    __syncthreads();

    for (int s = 0; s < NSTEP; ++s) {
        const int d = s & 1;
        _Float16* Lnext = lds + (d ? 0 : 8192);
        const _Float16* L = lds + (d ? 8192 : 0);
        if ((s + 1) < NSTEP) STAGE(s+1, Lnext);
        COMPUTE(L);
        __syncthreads();
    }

    #pragma unroll
    for (int mi = 0; mi < 4; ++mi) {
        #pragma unroll
        for (int nj = 0; nj < 2; ++nj) {
            int nn = n0 + wn*32 + nj*16 + lm;
            #pragma unroll
            for (int r = 0; r < 4; ++r) {
                int co = co0 + wm*64 + mi*16 + lk*4 + r;
                atomicAdd(&Clin[(size_t)co*12800 + nn], acc[mi][nj][r]);
            }
        }
    }
#undef STAGE
#undef COMPUTE
}

// ---------------- K2b: squared-norm partials per (b,u) from Clin+bias ----------------
__global__ void k_ssq(const float* __restrict__ Clin, const float* __restrict__ bias,
                      float* __restrict__ ssq) {
    __shared__ float r0[256], r1[256];
    int tid = threadIdx.x;
    int e = blockIdx.x*256 + tid;
    int co = e / 12800;
    int unit = co >> 5;
    float val = Clin[e] + bias[co];
    int n0b = (blockIdx.x % 50) * 256;
    int bn0 = n0b / 400;
    int nb  = (bn0+1)*400 - n0b;
    float v2 = val * val;
    bool hi = (tid >= nb);
    r0[tid] = hi ? 0.f : v2;
    r1[tid] = hi ? v2 : 0.f;
    __syncthreads();
    for (int st = 128; st > 0; st >>= 1) {
        if (tid < st) { r0[tid] += r0[tid+st]; r1[tid] += r1[tid+st]; }
        __syncthreads();
    }
    if (tid == 0) {
        atomicAdd(&ssq[bn0*8 + unit], r0[0]);
        if (nb < 256) atomicAdd(&ssq[(bn0+1)*8 + unit], r1[0]);
    }
}

// ---------------- K3: xq[p][b*8+u] = (Clin[co][n]+bias)*scl(b,u) ----------------
__global__ void k_xq2(const float* __restrict__ Clin, const float* __restrict__ bias,
                      const float* __restrict__ ssq, float* __restrict__ xq) {
    __shared__ float sT[32][257];
    __shared__ float sS[256];
    int p0 = blockIdx.x*32, tid = threadIdx.x;
    {
        float q = ssq[tid];
        sS[tid] = sqrtf(q) / (1.f + q);
    }
    __syncthreads();
    for (int r = 0; r < 32; ++r) {
        int e = r*256 + tid;
        int bu = e >> 5, pi = e & 31;
        int p = p0 + pi;
        int ch = p / 400, rr = p - ch*400;
        int unit = bu & 7, bn = bu >> 3;
        int co = unit*32 + ch;
        sT[pi][bu] = (Clin[(size_t)co*12800 + bn*400 + rr] + bias[co]) * sS[bu];
    }
    __syncthreads();
    for (int r = 0; r < 32; ++r)
        xq[(size_t)(p0+r)*256 + tid] = sT[r][tid];
}

// ---------------- K5: pass A — partial s_j; W in fp16 (v_fma_mix) ----------------
// grid (NBLK_A, 4): x = 64-p block, y = 40-os quarter. 256 thr = 8 g (5 os each) x 32 bq.
__global__ __launch_bounds__(256) void k_route_sj(const _Float16* __restrict__ Wh,
        const float* __restrict__ xq, const float* __restrict__ bij,
        const float* __restrict__ cden, float* __restrict__ sjp, int uniform) {
    int tid = threadIdx.x;
    int bq = tid & 31, g = tid >> 5;
    int os0 = blockIdx.y*40 + g*5;
    int o0 = os0 >> 4, o1 = (os0 + 4) >> 4;   // 5-wide window spans 1 or 2 o's
    float rd0, rd1;
    if (uniform) { rd0 = 1.f/12800.f; rd1 = rd0; }
    else         { rd0 = 1.f/cden[o0]; rd1 = 1.f/cden[o1]; }
    float acc[5];
    #pragma unroll
    for (int i = 0; i < 5; ++i) acc[i] = 0.f;
    int p0 = blockIdx.x * 64;
    for (int p = p0; p < p0+64; ++p) {
        const float4* xr = (const float4*)(xq + (size_t)p*256 + bq*8);
        float4 xa = xr[0], xb = xr[1];
        float c0 = uniform ? rd0 : __expf(bij[p*10+o0]) * rd0;
        float c1 = (o1 == o0) ? c0 : (uniform ? rd1 : __expf(bij[p*10+o1]) * rd1);
        const hv8* wr = (const hv8*)(Wh + (size_t)p*1280 + os0*8);
        #pragma unroll
        for (int i = 0; i < 5; ++i) {
            hv8 wv = wr[i];
            float uh = (float)wv[0]*xa.x + (float)wv[1]*xa.y + (float)wv[2]*xa.z + (float)wv[3]*xa.w
                     + (float)wv[4]*xb.x + (float)wv[5]*xb.y + (float)wv[6]*xb.z + (float)wv[7]*xb.w;
            int oi = (os0 + i) >> 4;
            acc[i] += (oi == o0 ? c0 : c1) * uh;
        }
    }
    float* outp = sjp + (size_t)blockIdx.x*5120 + bq*OSD + os0;
    #pragma unroll
    for (int i = 0; i < 5; ++i) outp[i] = acc[i];
}

// ---------------- K6: reduce partials -> s_j -> squash over O -> v (+out); zero cden ----------------
// grid 32 (one b each), 640 thr = 4 k-quarters x 160 e. Serial chain 200 -> 50.
__global__ void k_reduce_squash(const float* __restrict__ sjp, float* __restrict__ v,
                                float* __restrict__ cden,
                                float* __restrict__ dout, int writeOut) {
    __shared__ float ps[640];
    __shared__ float sc[16];
    int tid = threadIdx.x;
    int b = blockIdx.x;
    if (b == 0 && tid < 10) cden[tid] = 0.f;   // for next route_bij accumulation
    int q = tid / 160, el = tid - q*160;
    float s = 0.f;
    for (int k = q; k < NBLK_A; k += 4) s += sjp[(size_t)k*5120 + b*160 + el];
    ps[tid] = s;
    __syncthreads();
    float sfull = 0.f;
    if (tid < 160) {
        sfull = ps[tid] + ps[160+tid] + ps[320+tid] + ps[480+tid];
        ps[tid] = sfull;
    }
    __syncthreads();
    if (tid < 16) {
        float msq = 0.f;
        #pragma unroll
        for (int o = 0; o < 10; ++o) { float t_ = ps[o*16 + tid]; msq += t_*t_; }
        sc[tid] = sqrtf(msq) / (1.f + msq);
    }
    __syncthreads();
    if (tid < 160) {
        float val = sfull * sc[tid & 15];
        int e = b*160 + tid;
        v[e] = val;
        if (writeOut) dout[e] = val;
    }
}

// ---------------- K7: pass B — b_ij += mean_b sum_s u_hat*v ; W in fp16, single wreg pass ----------------
__global__ __launch_bounds__(320) void k_route_bij(const _Float16* __restrict__ Wh,
        const float* __restrict__ xq, const float* __restrict__ v,
        float* __restrict__ bij, float* __restrict__ cden) {
    __shared__ float sv[5120];
    __shared__ float sxq[32*260];
    __shared__ float red[320];
    int tid = threadIdx.x;
    int p0 = blockIdx.x*32;
    for (int e = tid; e < 5120; e += 320) sv[e] = v[e];
    for (int e = tid; e < 8192; e += 320) {
        int pl = e >> 8, bu = e & 255;
        sxq[pl*260 + bu] = xq[(size_t)(p0+pl)*256 + bu];
    }
    __syncthreads();
    int pl = tid / 10, o = tid - pl*10;
    int p = p0 + pl;
    const hv8* wr = (const hv8*)(Wh + (size_t)p*1280 + o*128);
    hv8 wreg[16];                 // 16 s-elements x 8 u halves = 32 VGPR
    #pragma unroll
    for (int i = 0; i < 16; ++i) wreg[i] = wr[i];
    float acc = 0.f;
    for (int bq = 0; bq < 32; ++bq) {
        float4 x0 = *(const float4*)&sxq[pl*260 + bq*8];
        float4 x1 = *(const float4*)&sxq[pl*260 + bq*8 + 4];
        #pragma unroll
        for (int sg = 0; sg < 4; ++sg) {
            float4 vs = *(const float4*)&sv[bq*160 + o*16 + sg*4];
            float vsv[4] = {vs.x, vs.y, vs.z, vs.w};
            #pragma unroll
            for (int s4 = 0; s4 < 4; ++s4) {
                hv8 wv = wreg[sg*4 + s4];
                float uh = (float)wv[0]*x0.x + (float)wv[1]*x0.y + (float)wv[2]*x0.z + (float)wv[3]*x0.w
                         + (float)wv[4]*x1.x + (float)wv[5]*x1.y + (float)wv[6]*x1.z + (float)wv[7]*x1.w;
                acc += uh * vsv[s4];
            }
        }
    }
    float bn_ = bij[p*10 + o] + acc * (1.f/32.f);
    bij[p*10 + o] = bn_;
    red[tid] = __expf(bn_);
    __syncthreads();
    if (tid < 10) {
        float s_ = 0.f;
        #pragma unroll
        for (int j = 0; j < 32; ++j) s_ += red[tid + j*10];
        atomicAdd(&cden[tid], s_);
    }
}

extern "C" void kernel_launch(void* const* d_in, const int* in_sizes, int n_in,
                              void* d_out, int out_size, void* d_ws, size_t ws_size,
                              hipStream_t stream) {
    const float* x   = (const float*)d_in[0];
    const float* c1w = (const float*)d_in[1];
    const float* c1b = (const float*)d_in[2];
    const float* pw  = (const float*)d_in[3];
    const float* pb  = (const float*)d_in[4];
    const float* Wd  = (const float*)d_in[5];
    float* out = (float*)d_out;

    // workspace map (bytes); total ~69.9 MB
    char* wsb = (char*)d_ws;
    _Float16* ht1 = (_Float16*)(wsb);                 // 12,845,056
    _Float16* Wk1 = (_Float16*)(wsb + 12845056);      // 10,616,832
    float* Clin = (float*)(wsb + 23461888);           // 13,107,200
    char* tailb = wsb + 36569088;
    float* bij   = (float*)tailb;                     // 128000 f
    float* ssq   = bij + 128000;                      // 256 f
    float* cden  = ssq + 256;                         // 16 f
    float* vv    = cden + 16;                         // 5120 f
    _Float16* Wh = (_Float16*)(wsb + 37102656);       // 32,768,000 (fp16 W_dig)
    // aliases over dead regions:
    float* xq  = (float*)(wsb);              // 13.1MB over ht1+head of Wk1 (dead after GEMM)
    float* sjp = (float*)(wsb + 23461888);   // over Clin (dead after xq2); 200*5120 f

    hipMemsetAsync(Clin, 0, 13107200, stream);
    hipMemsetAsync(bij, 0, (128000 + 256)*sizeof(float), stream);  // bij + ssq

    k_prep_wd<<<16000, 256, 0, stream>>>(Wd, Wh);
    k_prep_w<<<256, 256, 0, stream>>>(pw, Wk1);
    k_conv1<<<dim3(32,16), 256, 0, stream>>>(x, c1w, c1b, ht1);
    k_prim_mfma<<<dim3(100,2,8), 512, 0, stream>>>(ht1, Wk1, Clin);
    k_ssq<<<12800, 256, 0, stream>>>(Clin, pb, ssq);
    k_xq2<<<400, 256, 0, stream>>>(Clin, pb, ssq, xq);

    for (int it = 0; it < 3; ++it) {
        k_route_sj<<<dim3(NBLK_A,4), 256, 0, stream>>>(Wh, xq, bij, cden, sjp, it == 0 ? 1 : 0);
        k_reduce_squash<<<32, 640, 0, stream>>>(sjp, vv, cden, out, it == 2 ? 1 : 0);
        if (it < 2)
            k_route_bij<<<400, 320, 0, stream>>>(Wh, xq, vv, bij, cden);
    }
}

// Round 15
// 687.400 us; speedup vs baseline: 2.1107x; 1.1079x over previous
//
#include <hip/hip_runtime.h>
#include <math.h>

// ---- problem constants ----
static constexpr int PDIM = 12800;      // 32ch*400
static constexpr int OSD  = 160;        // 10*16
static constexpr int NBLK_A = 200;      // it0 pass-A p-blocks (64 p each)

typedef _Float16 hv8  __attribute__((ext_vector_type(8)));
typedef _Float16 hv4  __attribute__((ext_vector_type(4)));
typedef float    f32x4 __attribute__((ext_vector_type(4)));

__device__ __forceinline__ void gload16(const void* g, void* l) {
    __builtin_amdgcn_global_load_lds(
        (const __attribute__((address_space(1))) void*)g,
        (__attribute__((address_space(3))) void*)l, 16, 0, 0);
}

// ---------------- K0: prim_w[co][ci][81] -> Wk1[k][co][ci] fp16 ----------------
__global__ void k_prep_w(const float* __restrict__ w, _Float16* __restrict__ Wk1) {
    __shared__ float s[20736];          // one co-slice: [ci=256][k=81]
    int co = blockIdx.x, t = threadIdx.x;
    const float4* src = (const float4*)(w + (size_t)co*20736);
    float4* d4 = (float4*)s;
    for (int i = t; i < 5184; i += 256) d4[i] = src[i];
    __syncthreads();
    for (int k = 0; k < 81; ++k)
        Wk1[(size_t)k*65536 + co*256 + t] = (_Float16)s[t*81 + k];
}

// ---------------- K0b+K1 merged: blocks [0,16000) Wd->fp16; [16000,16512) conv1 ----------------
__global__ void k_prep_misc(const float* __restrict__ Wd, _Float16* __restrict__ Wh,
                            const float* __restrict__ x, const float* __restrict__ w,
                            const float* __restrict__ bias, _Float16* __restrict__ ht1) {
    __shared__ float sx[1296];
    __shared__ float sw[1296];
    int tid = threadIdx.x;
    if (blockIdx.x < 16000) {
        size_t i = ((size_t)blockIdx.x*256 + tid) * 4;   // 16,384,000 floats total
        float4 v = *(const float4*)(Wd + i);
        hv4 h;
        h[0] = (_Float16)v.x; h[1] = (_Float16)v.y;
        h[2] = (_Float16)v.z; h[3] = (_Float16)v.w;
        *(hv4*)(Wh + i) = h;
        return;
    }
    int bid2 = blockIdx.x - 16000;
    int b = bid2 >> 4, cog = bid2 & 15;
    for (int i = tid; i < 1296; i += 256) {
        sx[i] = x[b*1296 + i];
        sw[i] = w[cog*1296 + i];
    }
    __syncthreads();
    for (int pos = tid; pos < 784; pos += 256) {
        int y = pos / 28, xx = pos - y*28;
        float acc[16];
        #pragma unroll
        for (int c = 0; c < 16; ++c) acc[c] = 0.f;
        for (int ky = 0; ky < 9; ++ky) {
            #pragma unroll
            for (int kx = 0; kx < 9; ++kx) {
                float xv = sx[(y+ky)*36 + xx + kx];
                #pragma unroll
                for (int c = 0; c < 16; ++c)
                    acc[c] += xv * sw[c*81 + ky*9 + kx];
            }
        }
        #pragma unroll
        for (int c = 0; c < 16; ++c) {
            float r = acc[c] + bias[cog*16 + c];
            r = r > 0.f ? r : 0.f;
            ht1[((size_t)b*784 + pos)*256 + cog*16 + c] = (_Float16)r;
        }
    }
}

// ---------------- K2: primary conv as 81 shifted GEMMs, pure fp16 MFMA (frozen, r12) ----------------
__global__ __launch_bounds__(512, 8) void k_prim_mfma(
        const _Float16* __restrict__ ht1, const _Float16* __restrict__ Wk1,
        float* __restrict__ Clin) {
    // per-buffer (halfs): A @0 (4096), B @4096; BUF=8192 (16KB)
    __shared__ _Float16 lds[16384];
    const int t   = threadIdx.x;
    const int n0  = blockIdx.x * 128;
    const int co0 = blockIdx.y * 128;
    const int z   = blockIdx.z;
    const int klo = (z*81) >> 3, khi = ((z+1)*81) >> 3;
    const int NSTEP = (khi - klo) * 8;

    const int srow = t >> 2, slot = t & 3;
    const int g = slot ^ ((srow >> 1) & 3);
    const size_t aSrcOff = (size_t)(co0 + srow)*256 + g*8;
    const int n1 = n0 + srow;
    const int b1 = n1/400, rr1 = n1 - b1*400, y1 = rr1/20, x1 = rr1 - y1*20;
    const size_t bOff1 = ((size_t)b1*784 + y1*28 + x1)*256 + g*8;

    const int l = t & 63, w8 = t >> 6;
    const int wm = w8 >> 2, wn = w8 & 3;
    const int lm = l & 15, lk = l >> 4;
    int aoff[4], boff[2];
    #pragma unroll
    for (int i = 0; i < 4; ++i) {
        int ra = wm*64 + i*16 + lm;
        aoff[i] = ra*32 + ((lk ^ ((ra>>1)&3))*8);
    }
    #pragma unroll
    for (int j = 0; j < 2; ++j) {
        int rb = wn*32 + j*16 + lm;
        boff[j] = 4096 + rb*32 + ((lk ^ ((rb>>1)&3))*8);
    }

    f32x4 acc[4][2];
    #pragma unroll
    for (int i = 0; i < 4; ++i)
        #pragma unroll
        for (int j = 0; j < 2; ++j) { acc[i][j][0]=0.f; acc[i][j][1]=0.f; acc[i][j][2]=0.f; acc[i][j][3]=0.f; }

#define STAGE(S, LB) { int k_ = klo + ((S) >> 3), c_ = (S) & 7; \
        size_t ao = (size_t)k_*65536 + c_*32 + aSrcOff; \
        gload16(Wk1 + ao, (LB) + t*8); \
        int spk_ = (k_/9)*28 + (k_ - (k_/9)*9); \
        size_t so = (size_t)spk_*256 + c_*32; \
        gload16(ht1 + bOff1 + so, (LB) + 4096 + t*8); }

#define COMPUTE(L) { hv8 a1[4]; \
        _Pragma("unroll") for (int mi = 0; mi < 4; ++mi) \
            a1[mi] = *(const hv8*)((L) + aoff[mi]); \
        _Pragma("unroll") for (int nj = 0; nj < 2; ++nj) { \
            hv8 q1 = *(const hv8*)((L) + boff[nj]); \
            _Pragma("unroll") for (int mi = 0; mi < 4; ++mi) \
                acc[mi][nj] = __builtin_amdgcn_mfma_f32_16x16x32_f16(a1[mi], q1, acc[mi][nj], 0, 0, 0); } }

    STAGE(0, lds);
    __syncthreads();

    for (int s = 0; s < NSTEP; ++s) {
        const int d = s & 1;
        _Float16* Lnext = lds + (d ? 0 : 8192);
        const _Float16* L = lds + (d ? 8192 : 0);
        if ((s + 1) < NSTEP) STAGE(s+1, Lnext);
        COMPUTE(L);
        __syncthreads();
    }

    #pragma unroll
    for (int mi = 0; mi < 4; ++mi) {
        #pragma unroll
        for (int nj = 0; nj < 2; ++nj) {
            int nn = n0 + wn*32 + nj*16 + lm;
            #pragma unroll
            for (int r = 0; r < 4; ++r) {
                int co = co0 + wm*64 + mi*16 + lk*4 + r;
                atomicAdd(&Clin[(size_t)co*12800 + nn], acc[mi][nj][r]);
            }
        }
    }
#undef STAGE
#undef COMPUTE
}

// ---------------- K2b: squared-norm partials per (b,u) from Clin+bias ----------------
__global__ void k_ssq(const float* __restrict__ Clin, const float* __restrict__ bias,
                      float* __restrict__ ssq) {
    __shared__ float r0[256], r1[256];
    int tid = threadIdx.x;
    int e = blockIdx.x*256 + tid;
    int co = e / 12800;
    int unit = co >> 5;
    float val = Clin[e] + bias[co];
    int n0b = (blockIdx.x % 50) * 256;
    int bn0 = n0b / 400;
    int nb  = (bn0+1)*400 - n0b;
    float v2 = val * val;
    bool hi = (tid >= nb);
    r0[tid] = hi ? 0.f : v2;
    r1[tid] = hi ? v2 : 0.f;
    __syncthreads();
    for (int st = 128; st > 0; st >>= 1) {
        if (tid < st) { r0[tid] += r0[tid+st]; r1[tid] += r1[tid+st]; }
        __syncthreads();
    }
    if (tid == 0) {
        atomicAdd(&ssq[bn0*8 + unit], r0[0]);
        if (nb < 256) atomicAdd(&ssq[(bn0+1)*8 + unit], r1[0]);
    }
}

// ---------------- K3: xq[p][b*8+u] = (Clin[co][n]+bias)*scl(b,u) ----------------
__global__ void k_xq2(const float* __restrict__ Clin, const float* __restrict__ bias,
                      const float* __restrict__ ssq, float* __restrict__ xq) {
    __shared__ float sT[32][257];
    __shared__ float sS[256];
    int p0 = blockIdx.x*32, tid = threadIdx.x;
    {
        float q = ssq[tid];
        sS[tid] = sqrtf(q) / (1.f + q);
    }
    __syncthreads();
    for (int r = 0; r < 32; ++r) {
        int e = r*256 + tid;
        int bu = e >> 5, pi = e & 31;
        int p = p0 + pi;
        int ch = p / 400, rr = p - ch*400;
        int unit = bu & 7, bn = bu >> 3;
        int co = unit*32 + ch;
        sT[pi][bu] = (Clin[(size_t)co*12800 + bn*400 + rr] + bias[co]) * sS[bu];
    }
    __syncthreads();
    for (int r = 0; r < 32; ++r)
        xq[(size_t)(p0+r)*256 + tid] = sT[r][tid];
}

// ---------------- K5: it0 pass A — uniform c=1/P, partial s_j; also zero cdenA/B ----------------
// grid (NBLK_A, 4): x = 64-p block, y = 40-os quarter. 256 thr = 8 g (5 os each) x 32 bq.
// Runs after k_xq2 (ssq dead) and before any cden accumulation -> safe to zero here.
__global__ __launch_bounds__(256) void k_route_sj0(const _Float16* __restrict__ Wh,
        const float* __restrict__ xq, float* __restrict__ sjp,
        float* __restrict__ cdenAB) {
    int tid = threadIdx.x;
    if (blockIdx.x == 0 && blockIdx.y == 0 && tid < 32) cdenAB[tid] = 0.f;
    int bq = tid & 31, g = tid >> 5;
    int os0 = blockIdx.y*40 + g*5;
    float acc[5];
    #pragma unroll
    for (int i = 0; i < 5; ++i) acc[i] = 0.f;
    int p0 = blockIdx.x * 64;
    for (int p = p0; p < p0+64; ++p) {
        const float4* xr = (const float4*)(xq + (size_t)p*256 + bq*8);
        float4 xa = xr[0], xb = xr[1];
        const hv8* wr = (const hv8*)(Wh + (size_t)p*1280 + os0*8);
        #pragma unroll
        for (int i = 0; i < 5; ++i) {
            hv8 wv = wr[i];
            float uh = (float)wv[0]*xa.x + (float)wv[1]*xa.y + (float)wv[2]*xa.z + (float)wv[3]*xa.w
                     + (float)wv[4]*xb.x + (float)wv[5]*xb.y + (float)wv[6]*xb.z + (float)wv[7]*xb.w;
            acc[i] += uh;
        }
    }
    const float uc = 1.f / 12800.f;
    float* outp = sjp + (size_t)blockIdx.x*5120 + bq*OSD + os0;
    #pragma unroll
    for (int i = 0; i < 5; ++i) outp[i] = acc[i] * uc;
}

// ---------------- K6: reduce np partials -> s_j (/cden if useDen) -> squash over O -> v ----------------
// grid 32 (one b each), 640 thr = 4 k-quarters x 160 e.
__global__ void k_reduce_squash(const float* __restrict__ sjp, float* __restrict__ v,
                                const float* __restrict__ cden, int useDen, int np,
                                float* __restrict__ dout, int writeOut) {
    __shared__ float ps[640];
    __shared__ float sc[16];
    int tid = threadIdx.x;
    int b = blockIdx.x;
    int q = tid / 160, el = tid - q*160;
    float s = 0.f;
    for (int k = q; k < np; k += 4) s += sjp[(size_t)k*5120 + b*160 + el];
    ps[tid] = s;
    __syncthreads();
    if (tid < 160) {
        float sfull = ps[tid] + ps[160+tid] + ps[320+tid] + ps[480+tid];
        if (useDen) sfull *= 1.f / cden[tid >> 4];   // el = o*16+s -> o = el>>4
        ps[tid] = sfull;
    }
    __syncthreads();
    if (tid < 16) {
        float msq = 0.f;
        #pragma unroll
        for (int o = 0; o < 10; ++o) { float t_ = ps[o*16 + tid]; msq += t_*t_; }
        sc[tid] = sqrtf(msq) / (1.f + msq);
    }
    __syncthreads();
    if (tid < 160) {
        float val = ps[tid] * sc[tid & 15];
        int e = b*160 + tid;
        v[e] = val;
        if (writeOut) dout[e] = val;
    }
}

// ---------------- K7: fused pass B + next pass A ----------------
// phase 1 (thread = pl=tid/10, o=tid%10): EXACT r13 route_bij body; e=exp(b_new) -> LDS se.
// one barrier.
// phase 2 (thread = o2=tid>>5, bq=tid&31): unnormalized s~ partials = sum_p e_p * u_hat.
//   - 32 lanes sharing a W-address are a contiguous half-wave -> HW broadcast;
//     W slice is L1-hot from phase 1; sxq reused from LDS; single barrier.
//   - reduce_squash divides by cden afterwards (r6-validated normalize-after-sum).
__global__ __launch_bounds__(320) void k_fused_bs(const _Float16* __restrict__ Wh,
        const float* __restrict__ xq, const float* __restrict__ v,
        float* __restrict__ bij, float* __restrict__ cden, float* __restrict__ sjp) {
    __shared__ float sv[5120];
    __shared__ float sxq[32*260];
    __shared__ float red[320];
    __shared__ float se[320];
    int tid = threadIdx.x;
    int p0 = blockIdx.x*32;
    for (int e = tid; e < 5120; e += 320) sv[e] = v[e];
    for (int e = tid; e < 8192; e += 320) {
        int pl = e >> 8, bu = e & 255;
        sxq[pl*260 + bu] = xq[(size_t)(p0+pl)*256 + bu];
    }
    __syncthreads();
    // ---- phase 1: agree + bij update (r13 route_bij body) ----
    {
        int pl = tid / 10, o = tid - pl*10;
        int p = p0 + pl;
        const hv8* wr = (const hv8*)(Wh + (size_t)p*1280 + o*128);
        hv8 wreg[16];
        #pragma unroll
        for (int i = 0; i < 16; ++i) wreg[i] = wr[i];
        float acc = 0.f;
        for (int bq = 0; bq < 32; ++bq) {
            float4 x0 = *(const float4*)&sxq[pl*260 + bq*8];
            float4 x1 = *(const float4*)&sxq[pl*260 + bq*8 + 4];
            #pragma unroll
            for (int sg = 0; sg < 4; ++sg) {
                float4 vs = *(const float4*)&sv[bq*160 + o*16 + sg*4];
                float vsv[4] = {vs.x, vs.y, vs.z, vs.w};
                #pragma unroll
                for (int s4 = 0; s4 < 4; ++s4) {
                    hv8 wv = wreg[sg*4 + s4];
                    float uh = (float)wv[0]*x0.x + (float)wv[1]*x0.y + (float)wv[2]*x0.z + (float)wv[3]*x0.w
                             + (float)wv[4]*x1.x + (float)wv[5]*x1.y + (float)wv[6]*x1.z + (float)wv[7]*x1.w;
                    acc += uh * vsv[s4];
                }
            }
        }
        float bn_ = bij[p*10 + o] + acc * (1.f/32.f);
        bij[p*10 + o] = bn_;
        float e_ = __expf(bn_);
        se[tid] = e_;        // se[pl*10 + o]
        red[tid] = e_;
    }
    __syncthreads();
    if (tid < 10) {
        float s_ = 0.f;
        #pragma unroll
        for (int j = 0; j < 32; ++j) s_ += red[tid + j*10];
        atomicAdd(&cden[tid], s_);
    }
    // ---- phase 2: s~ partials; thread = (o2 = tid>>5, bq = tid&31) ----
    int o2 = tid >> 5, bq = tid & 31;
    float acc2[16];
    #pragma unroll
    for (int s = 0; s < 16; ++s) acc2[s] = 0.f;
    for (int pi = 0; pi < 32; ++pi) {
        float ee = se[pi*10 + o2];
        float4 x0 = *(const float4*)&sxq[pi*260 + bq*8];
        float4 x1 = *(const float4*)&sxq[pi*260 + bq*8 + 4];
        const hv8* wr2 = (const hv8*)(Wh + (size_t)(p0+pi)*1280 + o2*128);
        #pragma unroll
        for (int s = 0; s < 16; ++s) {
            hv8 wv = wr2[s];
            float uh = (float)wv[0]*x0.x + (float)wv[1]*x0.y + (float)wv[2]*x0.z + (float)wv[3]*x0.w
                     + (float)wv[4]*x1.x + (float)wv[5]*x1.y + (float)wv[6]*x1.z + (float)wv[7]*x1.w;
            acc2[s] += ee * uh;
        }
    }
    float* outp = sjp + (size_t)blockIdx.x*5120 + bq*OSD + o2*16;
    #pragma unroll
    for (int s = 0; s < 16; ++s) outp[s] = acc2[s];
}

extern "C" void kernel_launch(void* const* d_in, const int* in_sizes, int n_in,
                              void* d_out, int out_size, void* d_ws, size_t ws_size,
                              hipStream_t stream) {
    const float* x   = (const float*)d_in[0];
    const float* c1w = (const float*)d_in[1];
    const float* c1b = (const float*)d_in[2];
    const float* pw  = (const float*)d_in[3];
    const float* pb  = (const float*)d_in[4];
    const float* Wd  = (const float*)d_in[5];
    float* out = (float*)d_out;

    // workspace map (bytes); total 69,870,656 == r13's proven footprint
    char* wsb = (char*)d_ws;
    _Float16* ht1 = (_Float16*)(wsb);                 // 12,845,056
    _Float16* Wk1 = (_Float16*)(wsb + 12845056);      // 10,616,832
    float* Clin = (float*)(wsb + 23461888);           // 13,107,200
    char* tailb = wsb + 36569088;
    float* bij   = (float*)tailb;                     // 128,000 f -> ends 37,081,088
    float* ssq   = bij + 128000;                      // 256 f     -> ends 37,082,112
    float* vv    = ssq + 256;                         // 5,120 f   -> ends 37,102,592
    _Float16* Wh = (_Float16*)(wsb + 37102656);       // 32,768,000 B -> ends 69,870,656
    // aliases:
    float* cdenA = ssq;                      // ssq dead after k_xq2; zeroed in k_route_sj0
    float* cdenB = ssq + 16;
    float* xq  = (float*)(wsb);              // 13.1MB over ht1+head of Wk1 (dead after GEMM)
    float* sjp = (float*)(wsb + 23461888);   // over Clin (dead after xq2); 400*5120 f = 8.2MB

    hipMemsetAsync(Clin, 0, 13107200, stream);
    hipMemsetAsync(bij, 0, (128000 + 256)*sizeof(float), stream);  // bij + ssq

    k_prep_misc<<<16512, 256, 0, stream>>>(Wd, Wh, x, c1w, c1b, ht1);
    k_prep_w<<<256, 256, 0, stream>>>(pw, Wk1);
    k_prim_mfma<<<dim3(100,2,8), 512, 0, stream>>>(ht1, Wk1, Clin);
    k_ssq<<<12800, 256, 0, stream>>>(Clin, pb, ssq);
    k_xq2<<<400, 256, 0, stream>>>(Clin, pb, ssq, xq);

    // it0: uniform coupling (also zeroes cdenA/cdenB)
    k_route_sj0<<<dim3(NBLK_A,4), 256, 0, stream>>>(Wh, xq, sjp, cdenA);
    k_reduce_squash<<<32, 640, 0, stream>>>(sjp, vv, cdenA, 0, NBLK_A, out, 0);
    // it1: fused bij-update + unnormalized s~ (normalize-after-sum)
    k_fused_bs<<<400, 320, 0, stream>>>(Wh, xq, vv, bij, cdenA, sjp);
    k_reduce_squash<<<32, 640, 0, stream>>>(sjp, vv, cdenA, 1, 400, out, 0);
    // it2
    k_fused_bs<<<400, 320, 0, stream>>>(Wh, xq, vv, bij, cdenB, sjp);
    k_reduce_squash<<<32, 640, 0, stream>>>(sjp, vv, cdenB, 1, 400, out, 1);
}